// Round 1
// baseline (459.686 us; speedup 1.0000x reference)
//
#include <hip/hip_runtime.h>
#include <hip/hip_bf16.h>

#define HEADS 2
#define HIDD  128
#define DH    256      // HEADS*HIDD
#define NEG   0.2f
#define AGG_CAP 1024

// ---------------- CSR build ----------------

__global__ void k_degree(const int* __restrict__ dst, int* __restrict__ deg, int E) {
    int e = blockIdx.x * blockDim.x + threadIdx.x;
    if (e < E) atomicAdd(&deg[dst[e]], 1);
}

__global__ __launch_bounds__(1024) void k_scan(const int* __restrict__ deg,
                                               int* __restrict__ row_ptr,
                                               int* __restrict__ cursor, int n) {
    // n <= 32768: 1024 threads x 32 elems each
    __shared__ int lds[1024];
    int tid = threadIdx.x;
    int base = tid * 32;
    int local[32];
    int sum = 0;
#pragma unroll
    for (int k = 0; k < 32; ++k) {
        int i = base + k;
        int v = (i < n) ? deg[i] : 0;
        local[k] = sum;     // exclusive prefix within thread
        sum += v;
    }
    lds[tid] = sum;
    __syncthreads();
    for (int off = 1; off < 1024; off <<= 1) {
        int t = (tid >= off) ? lds[tid - off] : 0;
        __syncthreads();
        lds[tid] += t;
        __syncthreads();
    }
    int thread_off = lds[tid] - sum;   // exclusive across threads
#pragma unroll
    for (int k = 0; k < 32; ++k) {
        int i = base + k;
        if (i < n) {
            int rp = thread_off + local[k];
            row_ptr[i] = rp;
            cursor[i]  = rp;
        }
    }
    if (tid == 1023) row_ptr[n] = lds[1023];
}

__global__ void k_fill(const int* __restrict__ dst, int* __restrict__ cursor,
                       int* __restrict__ eidx, int E) {
    int e = blockIdx.x * blockDim.x + threadIdx.x;
    if (e < E) {
        int pos = atomicAdd(&cursor[dst[e]], 1);
        eidx[pos] = e;
    }
}

// ---------------- GEMM: C[M,256] = A[M,K] @ B[K,256] ----------------
// BM=64, BN=128, BK=32; 256 threads; micro-tile 4 rows x 8 cols.

#define BM 64
#define BN 128
#define BK 32

template<int K, bool CONCAT>
__global__ __launch_bounds__(256) void k_gemm(const float* __restrict__ A,
                                              const float* __restrict__ A2,
                                              const float* __restrict__ B,
                                              float* __restrict__ C, int M) {
    __shared__ float As[BK][BM + 4];    // transposed: As[k][m], stride 68 (16B-aligned rows)
    __shared__ float Bs[BK][BN + 4];    // Bs[k][n], stride 132

    int row0 = blockIdx.x * BM;
    int col0 = blockIdx.y * BN;
    int tid = threadIdx.x;
    int tx = tid & 15;    // col group: cols tx*8 .. tx*8+7
    int ty = tid >> 4;    // row group: rows ty*4 .. ty*4+3

    float acc[4][8];
#pragma unroll
    for (int i = 0; i < 4; ++i)
#pragma unroll
        for (int j = 0; j < 8; ++j) acc[i][j] = 0.f;

    for (int k0 = 0; k0 < K; k0 += BK) {
        // A tile: 64 rows x 32 k  (512 float4, 2 per thread)
#pragma unroll
        for (int it = 0; it < 2; ++it) {
            int l = tid + it * 256;
            int r  = l >> 3;
            int kc = (l & 7) << 2;
            int gr = row0 + r;
            int gk = k0 + kc;
            float4 v = make_float4(0.f, 0.f, 0.f, 0.f);
            if (gr < M) {
                if (CONCAT) {
                    const float* s = (gk < 64) ? (A + (size_t)gr * 64 + gk)
                                               : (A2 + (size_t)gr * 64 + (gk - 64));
                    v = *reinterpret_cast<const float4*>(s);
                } else {
                    v = *reinterpret_cast<const float4*>(A + (size_t)gr * K + gk);
                }
            }
            As[kc + 0][r] = v.x;
            As[kc + 1][r] = v.y;
            As[kc + 2][r] = v.z;
            As[kc + 3][r] = v.w;
        }
        // B tile: 32 k-rows x 128 cols (1024 float4, 4 per thread)
#pragma unroll
        for (int it = 0; it < 4; ++it) {
            int l = tid + it * 256;
            int kr = l >> 5;
            int jc = (l & 31) << 2;
            float4 v = *reinterpret_cast<const float4*>(B + (size_t)(k0 + kr) * DH + col0 + jc);
            *reinterpret_cast<float4*>(&Bs[kr][jc]) = v;
        }
        __syncthreads();

#pragma unroll
        for (int k = 0; k < BK; ++k) {
            float4 a  = *reinterpret_cast<const float4*>(&As[k][ty * 4]);
            float4 b0 = *reinterpret_cast<const float4*>(&Bs[k][tx * 8]);
            float4 b1 = *reinterpret_cast<const float4*>(&Bs[k][tx * 8 + 4]);
            float av[4] = {a.x, a.y, a.z, a.w};
            float bv[8] = {b0.x, b0.y, b0.z, b0.w, b1.x, b1.y, b1.z, b1.w};
#pragma unroll
            for (int i = 0; i < 4; ++i)
#pragma unroll
                for (int j = 0; j < 8; ++j)
                    acc[i][j] = fmaf(av[i], bv[j], acc[i][j]);
        }
        __syncthreads();
    }

#pragma unroll
    for (int i = 0; i < 4; ++i) {
        int gr = row0 + ty * 4 + i;
        if (gr < M) {
            float4 o0 = make_float4(acc[i][0], acc[i][1], acc[i][2], acc[i][3]);
            float4 o1 = make_float4(acc[i][4], acc[i][5], acc[i][6], acc[i][7]);
            float* cp = C + (size_t)gr * DH + col0 + tx * 8;
            *reinterpret_cast<float4*>(cp)     = o0;
            *reinterpret_cast<float4*>(cp + 4) = o1;
        }
    }
}

// ---------------- el/er: per-node attention dots ----------------

__global__ __launch_bounds__(256) void k_eler(const float* __restrict__ h,
                                              const float* __restrict__ al,
                                              const float* __restrict__ ar,
                                              float* __restrict__ el,
                                              float* __restrict__ er) {
    int node = blockIdx.x;
    int tid = threadIdx.x;
    float v = h[(size_t)node * DH + tid];
    float sl = v * al[tid];
    float sr = v * ar[tid];
#pragma unroll
    for (int off = 32; off; off >>= 1) {
        sl += __shfl_xor(sl, off);
        sr += __shfl_xor(sr, off);
    }
    __shared__ float red[4][2];
    int wv = tid >> 6;
    if ((tid & 63) == 0) { red[wv][0] = sl; red[wv][1] = sr; }
    __syncthreads();
    if (tid == 0) {
        el[node * 2 + 0] = red[0][0] + red[1][0];
        er[node * 2 + 0] = red[0][1] + red[1][1];
    }
    if (tid == 128) {
        el[node * 2 + 1] = red[2][0] + red[3][0];
        er[node * 2 + 1] = red[2][1] + red[3][1];
    }
}

// ---------------- aggregation: per-dst softmax + weighted scatter-sum ----------------

__global__ __launch_bounds__(256) void k_agg(const float* __restrict__ h,
                                             const float* __restrict__ el,
                                             const float* __restrict__ er,
                                             const int* __restrict__ row_ptr,
                                             const int* __restrict__ eidx,
                                             const int* __restrict__ src,
                                             const float* __restrict__ bias,
                                             float* __restrict__ g) {
    int node = blockIdx.x;
    int tid = threadIdx.x;
    int beg = row_ptr[node];
    int deg = row_ptr[node + 1] - beg;

    __shared__ int   s_src[AGG_CAP];
    __shared__ float s_ex[AGG_CAP][2];
    __shared__ float s_red[4][2];

    float er0 = er[node * 2 + 0];
    float er1 = er[node * 2 + 1];

    // phase 1: scores + per-thread max
    float m0 = -__builtin_inff(), m1 = -__builtin_inff();
    for (int i = tid; i < deg; i += 256) {
        int e = eidx[beg + i];
        int s = src[e];
        float sc0 = el[s * 2 + 0] + er0;
        float sc1 = el[s * 2 + 1] + er1;
        sc0 = sc0 > 0.f ? sc0 : NEG * sc0;
        sc1 = sc1 > 0.f ? sc1 : NEG * sc1;
        if (i < AGG_CAP) { s_src[i] = s; s_ex[i][0] = sc0; s_ex[i][1] = sc1; }
        m0 = fmaxf(m0, sc0);
        m1 = fmaxf(m1, sc1);
    }
#pragma unroll
    for (int off = 32; off; off >>= 1) {
        m0 = fmaxf(m0, __shfl_xor(m0, off));
        m1 = fmaxf(m1, __shfl_xor(m1, off));
    }
    int wv = tid >> 6;
    if ((tid & 63) == 0) { s_red[wv][0] = m0; s_red[wv][1] = m1; }
    __syncthreads();
    float M0 = fmaxf(fmaxf(s_red[0][0], s_red[1][0]), fmaxf(s_red[2][0], s_red[3][0]));
    float M1 = fmaxf(fmaxf(s_red[0][1], s_red[1][1]), fmaxf(s_red[2][1], s_red[3][1]));
    __syncthreads();

    // phase 2: exp + sum
    float sum0 = 0.f, sum1 = 0.f;
    for (int i = tid; i < deg; i += 256) {
        float sc0, sc1;
        if (i < AGG_CAP) { sc0 = s_ex[i][0]; sc1 = s_ex[i][1]; }
        else {
            int e = eidx[beg + i];
            int s = src[e];
            sc0 = el[s * 2 + 0] + er0;
            sc1 = el[s * 2 + 1] + er1;
            sc0 = sc0 > 0.f ? sc0 : NEG * sc0;
            sc1 = sc1 > 0.f ? sc1 : NEG * sc1;
        }
        float e0 = __expf(sc0 - M0);
        float e1 = __expf(sc1 - M1);
        if (i < AGG_CAP) { s_ex[i][0] = e0; s_ex[i][1] = e1; }
        sum0 += e0;
        sum1 += e1;
    }
#pragma unroll
    for (int off = 32; off; off >>= 1) {
        sum0 += __shfl_xor(sum0, off);
        sum1 += __shfl_xor(sum1, off);
    }
    if ((tid & 63) == 0) { s_red[wv][0] = sum0; s_red[wv][1] = sum1; }
    __syncthreads();
    float S0 = s_red[0][0] + s_red[1][0] + s_red[2][0] + s_red[3][0];
    float S1 = s_red[0][1] + s_red[1][1] + s_red[2][1] + s_red[3][1];
    float inv0 = S0 > 0.f ? 1.f / S0 : 0.f;
    float inv1 = S1 > 0.f ? 1.f / S1 : 0.f;

    // phase 3: weighted accumulation; thread owns feature `tid`
    int hh = tid >> 7;
    float invS = hh ? inv1 : inv0;
    float M    = hh ? M1 : M0;
    float erh  = hh ? er1 : er0;
    float acc = 0.f;
#pragma unroll 4
    for (int i = 0; i < deg; ++i) {
        int s;
        float a;
        if (i < AGG_CAP) {
            s = s_src[i];
            a = s_ex[i][hh] * invS;
        } else {
            int e = eidx[beg + i];
            s = src[e];
            float sc = el[s * 2 + hh] + erh;
            sc = sc > 0.f ? sc : NEG * sc;
            a = __expf(sc - M) * invS;
        }
        acc = fmaf(a, h[(size_t)s * DH + tid], acc);
    }
    float o = acc + bias[tid];
    g[(size_t)node * DH + tid] = fmaxf(o, 0.f);
}

// ---------------- final classifier ----------------

__global__ __launch_bounds__(256) void k_proj(const float* __restrict__ g2,
                                              const float* __restrict__ fcW,
                                              float* __restrict__ p, int n) {
    int gid = blockIdx.x * blockDim.x + threadIdx.x;
    int wid = gid >> 6;
    int lane = threadIdx.x & 63;
    if (wid >= n) return;
    const float* row = g2 + (size_t)wid * DH;
    float a0 = 0.f, a1 = 0.f, a2 = 0.f, a3 = 0.f;
#pragma unroll
    for (int k = 0; k < 4; ++k) {
        int d = lane + k * 64;
        float v = row[d];
        float2 wt = *reinterpret_cast<const float2*>(&fcW[d * 2]);
        float2 wb = *reinterpret_cast<const float2*>(&fcW[(DH + d) * 2]);
        a0 = fmaf(v, wt.x, a0);
        a1 = fmaf(v, wt.y, a1);
        a2 = fmaf(v, wb.x, a2);
        a3 = fmaf(v, wb.y, a3);
    }
#pragma unroll
    for (int off = 32; off; off >>= 1) {
        a0 += __shfl_xor(a0, off);
        a1 += __shfl_xor(a1, off);
        a2 += __shfl_xor(a2, off);
        a3 += __shfl_xor(a3, off);
    }
    if (lane == 0) {
        float4 v = make_float4(a0, a1, a2, a3);
        *reinterpret_cast<float4*>(&p[(size_t)wid * 4]) = v;
    }
}

__global__ void k_edgeout(const float* __restrict__ p,
                          const int* __restrict__ src,
                          const int* __restrict__ dst,
                          const float* __restrict__ fcb,
                          float* __restrict__ out, int E) {
    int e = blockIdx.x * blockDim.x + threadIdx.x;
    if (e >= E) return;
    int s = src[e], d = dst[e];
    float2 ps = *reinterpret_cast<const float2*>(&p[(size_t)s * 4]);
    float2 pd = *reinterpret_cast<const float2*>(&p[(size_t)d * 4 + 2]);
    float2 o;
    o.x = ps.x + pd.x + fcb[0];
    o.y = ps.y + pd.y + fcb[1];
    *reinterpret_cast<float2*>(&out[(size_t)e * 2]) = o;
}

// ---------------- launch ----------------

extern "C" void kernel_launch(void* const* d_in, const int* in_sizes, int n_in,
                              void* d_out, int out_size, void* d_ws, size_t ws_size,
                              hipStream_t stream) {
    const float* x   = (const float*)d_in[0];
    const float* rep = (const float*)d_in[1];
    const int*   src = (const int*)d_in[2];
    const int*   dst = (const int*)d_in[3];
    const float* W1  = (const float*)d_in[4];
    const float* al1 = (const float*)d_in[5];
    const float* ar1 = (const float*)d_in[6];
    const float* b1  = (const float*)d_in[7];
    const float* W2  = (const float*)d_in[8];
    const float* al2 = (const float*)d_in[9];
    const float* ar2 = (const float*)d_in[10];
    const float* b2  = (const float*)d_in[11];
    const float* fcW = (const float*)d_in[12];
    const float* fcb = (const float*)d_in[13];
    float* out = (float*)d_out;

    int N = in_sizes[0] / 64;   // 25000
    int E = in_sizes[2];        // 400000

    char* ws = (char*)d_ws;
    size_t off = 0;
    auto alloc = [&](size_t bytes) -> void* {
        void* ptr = ws + off;
        off = (off + bytes + 255) & ~(size_t)255;
        return ptr;
    };
    int*   deg     = (int*)alloc((size_t)N * 4);
    int*   row_ptr = (int*)alloc((size_t)(N + 1) * 4);
    int*   cursor  = (int*)alloc((size_t)N * 4);
    int*   eidx    = (int*)alloc((size_t)E * 4);
    float* hbuf    = (float*)alloc((size_t)N * DH * 4);
    float* gbuf    = (float*)alloc((size_t)N * DH * 4);
    float* el      = (float*)alloc((size_t)N * 2 * 4);
    float* er      = (float*)alloc((size_t)N * 2 * 4);
    float* p       = (float*)alloc((size_t)N * 4 * 4);

    hipMemsetAsync(deg, 0, (size_t)N * 4, stream);

    int eb = (E + 255) / 256;
    k_degree<<<eb, 256, 0, stream>>>(dst, deg, E);
    k_scan<<<1, 1024, 0, stream>>>(deg, row_ptr, cursor, N);
    k_fill<<<eb, 256, 0, stream>>>(dst, cursor, eidx, E);

    dim3 ggrid((N + BM - 1) / BM, DH / BN);
    // layer 1
    k_gemm<128, true><<<ggrid, 256, 0, stream>>>(x, rep, W1, hbuf, N);
    k_eler<<<N, 256, 0, stream>>>(hbuf, al1, ar1, el, er);
    k_agg<<<N, 256, 0, stream>>>(hbuf, el, er, row_ptr, eidx, src, b1, gbuf);
    // layer 2
    k_gemm<256, false><<<ggrid, 256, 0, stream>>>(gbuf, nullptr, W2, hbuf, N);
    k_eler<<<N, 256, 0, stream>>>(hbuf, al2, ar2, el, er);
    k_agg<<<N, 256, 0, stream>>>(hbuf, el, er, row_ptr, eidx, src, b2, gbuf);
    // classifier
    k_proj<<<(N * 64 + 255) / 256, 256, 0, stream>>>(gbuf, fcW, p, N);
    k_edgeout<<<eb, 256, 0, stream>>>(p, src, dst, fcb, out, E);
}

// Round 2
// 394.405 us; speedup vs baseline: 1.1655x; 1.1655x over previous
//
#include <hip/hip_runtime.h>
#include <hip/hip_bf16.h>

#define HEADS 2
#define HIDD  128
#define DH    256      // HEADS*HIDD
#define NEG   0.2f
#define CAP   128      // per-node LDS edge cache (P[deg>128] ~ 0 for Poisson(16); fallback path exists)

// ---------------- CSR build ----------------

__global__ void k_degree(const int* __restrict__ dst, int* __restrict__ deg, int E) {
    int e = blockIdx.x * blockDim.x + threadIdx.x;
    if (e < E) atomicAdd(&deg[dst[e]], 1);
}

__global__ __launch_bounds__(1024) void k_scan(const int* __restrict__ deg,
                                               int* __restrict__ row_ptr,
                                               int* __restrict__ cursor, int n) {
    // n <= 32768: 1024 threads x 32 elems each
    __shared__ int lds[1024];
    int tid = threadIdx.x;
    int base = tid * 32;
    int local[32];
    int sum = 0;
#pragma unroll
    for (int k = 0; k < 32; ++k) {
        int i = base + k;
        int v = (i < n) ? deg[i] : 0;
        local[k] = sum;
        sum += v;
    }
    lds[tid] = sum;
    __syncthreads();
    for (int off = 1; off < 1024; off <<= 1) {
        int t = (tid >= off) ? lds[tid - off] : 0;
        __syncthreads();
        lds[tid] += t;
        __syncthreads();
    }
    int thread_off = lds[tid] - sum;
#pragma unroll
    for (int k = 0; k < 32; ++k) {
        int i = base + k;
        if (i < n) {
            int rp = thread_off + local[k];
            row_ptr[i] = rp;
            cursor[i]  = rp;
        }
    }
    if (tid == 1023) row_ptr[n] = lds[1023];
}

__global__ void k_fill(const int* __restrict__ src, const int* __restrict__ dst,
                       int* __restrict__ cursor, int* __restrict__ csr_src, int E) {
    int e = blockIdx.x * blockDim.x + threadIdx.x;
    if (e < E) {
        int pos = atomicAdd(&cursor[dst[e]], 1);
        csr_src[pos] = src[e];
    }
}

// ---------------- GEMM: C[M,256] = A[M,K] @ B[K,256] ----------------

#define BM 64
#define BN 128
#define BK 32

template<int K, bool CONCAT>
__global__ __launch_bounds__(256) void k_gemm(const float* __restrict__ A,
                                              const float* __restrict__ A2,
                                              const float* __restrict__ B,
                                              float* __restrict__ C, int M) {
    __shared__ float As[BK][BM + 4];
    __shared__ float Bs[BK][BN + 4];

    int row0 = blockIdx.x * BM;
    int col0 = blockIdx.y * BN;
    int tid = threadIdx.x;
    int tx = tid & 15;
    int ty = tid >> 4;

    float acc[4][8];
#pragma unroll
    for (int i = 0; i < 4; ++i)
#pragma unroll
        for (int j = 0; j < 8; ++j) acc[i][j] = 0.f;

    for (int k0 = 0; k0 < K; k0 += BK) {
#pragma unroll
        for (int it = 0; it < 2; ++it) {
            int l = tid + it * 256;
            int r  = l >> 3;
            int kc = (l & 7) << 2;
            int gr = row0 + r;
            int gk = k0 + kc;
            float4 v = make_float4(0.f, 0.f, 0.f, 0.f);
            if (gr < M) {
                if (CONCAT) {
                    const float* s = (gk < 64) ? (A + (size_t)gr * 64 + gk)
                                               : (A2 + (size_t)gr * 64 + (gk - 64));
                    v = *reinterpret_cast<const float4*>(s);
                } else {
                    v = *reinterpret_cast<const float4*>(A + (size_t)gr * K + gk);
                }
            }
            As[kc + 0][r] = v.x;
            As[kc + 1][r] = v.y;
            As[kc + 2][r] = v.z;
            As[kc + 3][r] = v.w;
        }
#pragma unroll
        for (int it = 0; it < 4; ++it) {
            int l = tid + it * 256;
            int kr = l >> 5;
            int jc = (l & 31) << 2;
            float4 v = *reinterpret_cast<const float4*>(B + (size_t)(k0 + kr) * DH + col0 + jc);
            *reinterpret_cast<float4*>(&Bs[kr][jc]) = v;
        }
        __syncthreads();

#pragma unroll
        for (int k = 0; k < BK; ++k) {
            float4 a  = *reinterpret_cast<const float4*>(&As[k][ty * 4]);
            float4 b0 = *reinterpret_cast<const float4*>(&Bs[k][tx * 8]);
            float4 b1 = *reinterpret_cast<const float4*>(&Bs[k][tx * 8 + 4]);
            float av[4] = {a.x, a.y, a.z, a.w};
            float bv[8] = {b0.x, b0.y, b0.z, b0.w, b1.x, b1.y, b1.z, b1.w};
#pragma unroll
            for (int i = 0; i < 4; ++i)
#pragma unroll
                for (int j = 0; j < 8; ++j)
                    acc[i][j] = fmaf(av[i], bv[j], acc[i][j]);
        }
        __syncthreads();
    }

#pragma unroll
    for (int i = 0; i < 4; ++i) {
        int gr = row0 + ty * 4 + i;
        if (gr < M) {
            float4 o0 = make_float4(acc[i][0], acc[i][1], acc[i][2], acc[i][3]);
            float4 o1 = make_float4(acc[i][4], acc[i][5], acc[i][6], acc[i][7]);
            float* cp = C + (size_t)gr * DH + col0 + tx * 8;
            *reinterpret_cast<float4*>(cp)     = o0;
            *reinterpret_cast<float4*>(cp + 4) = o1;
        }
    }
}

// ---------------- el/er: per-node attention dots (wave per node) ----------------

__global__ __launch_bounds__(256) void k_eler(const float* __restrict__ h,
                                              const float* __restrict__ al,
                                              const float* __restrict__ ar,
                                              float2* __restrict__ el2,
                                              float2* __restrict__ er2, int N) {
    int w = threadIdx.x >> 6, lane = threadIdx.x & 63;
    int node = blockIdx.x * 4 + w;
    if (node >= N) return;
    float4 v = *reinterpret_cast<const float4*>(h + (size_t)node * DH + lane * 4);
    float4 a = *reinterpret_cast<const float4*>(al + lane * 4);
    float4 r = *reinterpret_cast<const float4*>(ar + lane * 4);
    float sl = v.x * a.x + v.y * a.y + v.z * a.z + v.w * a.w;
    float sr = v.x * r.x + v.y * r.y + v.z * r.z + v.w * r.w;
#pragma unroll
    for (int off = 16; off; off >>= 1) {
        sl += __shfl_xor(sl, off);
        sr += __shfl_xor(sr, off);
    }
    // lane 0 holds head0 sum, lane 32 holds head1 sum
    float el0 = __shfl(sl, 0), el1 = __shfl(sl, 32);
    float er0 = __shfl(sr, 0), er1 = __shfl(sr, 32);
    if (lane == 0) el2[node] = make_float2(el0, el1);
    if (lane == 1) er2[node] = make_float2(er0, er1);
}

// ---------------- aggregation: wave-per-node softmax + float4 gather ----------------

__global__ __launch_bounds__(256) void k_agg(const float* __restrict__ h,
                                             const float2* __restrict__ el2,
                                             const float2* __restrict__ er2,
                                             const int* __restrict__ row_ptr,
                                             const int* __restrict__ csr_src,
                                             const float* __restrict__ bias,
                                             float* __restrict__ g, int N) {
    __shared__ int    s_idx[4][CAP];
    __shared__ float2 s_a[4][CAP];

    int w = threadIdx.x >> 6, lane = threadIdx.x & 63;
    int node = blockIdx.x * 4 + w;
    if (node >= N) return;    // no block-wide syncs anywhere — safe
    int beg = row_ptr[node];
    int deg = row_ptr[node + 1] - beg;
    float2 er = er2[node];
    bool lo = lane < 32;

    // phase 1: scores + wave max
    float m0 = -__builtin_inff(), m1 = -__builtin_inff();
    for (int i = lane; i < deg; i += 64) {
        int s = csr_src[beg + i];
        float2 el = el2[s];
        float sc0 = el.x + er.x; sc0 = sc0 > 0.f ? sc0 : NEG * sc0;
        float sc1 = el.y + er.y; sc1 = sc1 > 0.f ? sc1 : NEG * sc1;
        if (i < CAP) { s_idx[w][i] = s; s_a[w][i] = make_float2(sc0, sc1); }
        m0 = fmaxf(m0, sc0);
        m1 = fmaxf(m1, sc1);
    }
#pragma unroll
    for (int off = 32; off; off >>= 1) {
        m0 = fmaxf(m0, __shfl_xor(m0, off));
        m1 = fmaxf(m1, __shfl_xor(m1, off));
    }

    // phase 2: exp + wave sum (store exp; divide once in epilogue)
    float sum0 = 0.f, sum1 = 0.f;
    for (int i = lane; i < deg; i += 64) {
        float2 sc;
        if (i < CAP) sc = s_a[w][i];
        else {
            int s = csr_src[beg + i];
            float2 el = el2[s];
            sc.x = el.x + er.x; sc.x = sc.x > 0.f ? sc.x : NEG * sc.x;
            sc.y = el.y + er.y; sc.y = sc.y > 0.f ? sc.y : NEG * sc.y;
        }
        float e0 = __expf(sc.x - m0);
        float e1 = __expf(sc.y - m1);
        if (i < CAP) s_a[w][i] = make_float2(e0, e1);
        sum0 += e0;
        sum1 += e1;
    }
#pragma unroll
    for (int off = 32; off; off >>= 1) {
        sum0 += __shfl_xor(sum0, off);
        sum1 += __shfl_xor(sum1, off);
    }
    float S   = lo ? sum0 : sum1;
    float inv = S > 0.f ? 1.f / S : 0.f;
    float mh  = lo ? m0 : m1;
    float erh = lo ? er.x : er.y;

    // phase 3: float4 gather, 4 edges in flight
    const float* hp = h + (size_t)lane * 4;
    float4 acc = make_float4(0.f, 0.f, 0.f, 0.f);

#define FETCH(I, S_, A_)                                                    \
    do {                                                                     \
        int _i = (I);                                                        \
        if (_i < CAP) {                                                      \
            S_ = s_idx[w][_i];                                               \
            float2 _a2 = s_a[w][_i];                                         \
            A_ = lo ? _a2.x : _a2.y;                                         \
        } else {                                                             \
            S_ = csr_src[beg + _i];                                          \
            float2 _el = el2[S_];                                            \
            float _sc = (lo ? _el.x : _el.y) + erh;                          \
            _sc = _sc > 0.f ? _sc : NEG * _sc;                               \
            A_ = __expf(_sc - mh);                                           \
        }                                                                    \
    } while (0)

    int i = 0;
    for (; i + 4 <= deg; i += 4) {
        int s0, s1, s2, s3;
        float a0, a1, a2, a3;
        FETCH(i,     s0, a0);
        FETCH(i + 1, s1, a1);
        FETCH(i + 2, s2, a2);
        FETCH(i + 3, s3, a3);
        float4 v0 = *reinterpret_cast<const float4*>(hp + (size_t)s0 * DH);
        float4 v1 = *reinterpret_cast<const float4*>(hp + (size_t)s1 * DH);
        float4 v2 = *reinterpret_cast<const float4*>(hp + (size_t)s2 * DH);
        float4 v3 = *reinterpret_cast<const float4*>(hp + (size_t)s3 * DH);
        acc.x = fmaf(a0, v0.x, acc.x); acc.y = fmaf(a0, v0.y, acc.y);
        acc.z = fmaf(a0, v0.z, acc.z); acc.w = fmaf(a0, v0.w, acc.w);
        acc.x = fmaf(a1, v1.x, acc.x); acc.y = fmaf(a1, v1.y, acc.y);
        acc.z = fmaf(a1, v1.z, acc.z); acc.w = fmaf(a1, v1.w, acc.w);
        acc.x = fmaf(a2, v2.x, acc.x); acc.y = fmaf(a2, v2.y, acc.y);
        acc.z = fmaf(a2, v2.z, acc.z); acc.w = fmaf(a2, v2.w, acc.w);
        acc.x = fmaf(a3, v3.x, acc.x); acc.y = fmaf(a3, v3.y, acc.y);
        acc.z = fmaf(a3, v3.z, acc.z); acc.w = fmaf(a3, v3.w, acc.w);
    }
    for (; i < deg; ++i) {
        int s;
        float a;
        FETCH(i, s, a);
        float4 v = *reinterpret_cast<const float4*>(hp + (size_t)s * DH);
        acc.x = fmaf(a, v.x, acc.x); acc.y = fmaf(a, v.y, acc.y);
        acc.z = fmaf(a, v.z, acc.z); acc.w = fmaf(a, v.w, acc.w);
    }
#undef FETCH

    float4 b = *reinterpret_cast<const float4*>(bias + lane * 4);
    float4 o;
    o.x = fmaxf(fmaf(acc.x, inv, b.x), 0.f);
    o.y = fmaxf(fmaf(acc.y, inv, b.y), 0.f);
    o.z = fmaxf(fmaf(acc.z, inv, b.z), 0.f);
    o.w = fmaxf(fmaf(acc.w, inv, b.w), 0.f);
    *reinterpret_cast<float4*>(g + (size_t)node * DH + lane * 4) = o;
}

// ---------------- final classifier ----------------

__global__ __launch_bounds__(256) void k_proj(const float* __restrict__ g2,
                                              const float* __restrict__ fcW,
                                              float* __restrict__ p, int n) {
    int gid = blockIdx.x * blockDim.x + threadIdx.x;
    int wid = gid >> 6;
    int lane = threadIdx.x & 63;
    if (wid >= n) return;
    const float* row = g2 + (size_t)wid * DH;
    float a0 = 0.f, a1 = 0.f, a2 = 0.f, a3 = 0.f;
#pragma unroll
    for (int k = 0; k < 4; ++k) {
        int d = lane + k * 64;
        float v = row[d];
        float2 wt = *reinterpret_cast<const float2*>(&fcW[d * 2]);
        float2 wb = *reinterpret_cast<const float2*>(&fcW[(DH + d) * 2]);
        a0 = fmaf(v, wt.x, a0);
        a1 = fmaf(v, wt.y, a1);
        a2 = fmaf(v, wb.x, a2);
        a3 = fmaf(v, wb.y, a3);
    }
#pragma unroll
    for (int off = 32; off; off >>= 1) {
        a0 += __shfl_xor(a0, off);
        a1 += __shfl_xor(a1, off);
        a2 += __shfl_xor(a2, off);
        a3 += __shfl_xor(a3, off);
    }
    if (lane == 0) {
        float4 v = make_float4(a0, a1, a2, a3);
        *reinterpret_cast<float4*>(&p[(size_t)wid * 4]) = v;
    }
}

__global__ void k_edgeout(const float* __restrict__ p,
                          const int* __restrict__ src,
                          const int* __restrict__ dst,
                          const float* __restrict__ fcb,
                          float* __restrict__ out, int E) {
    int e = blockIdx.x * blockDim.x + threadIdx.x;
    if (e >= E) return;
    int s = src[e], d = dst[e];
    float2 ps = *reinterpret_cast<const float2*>(&p[(size_t)s * 4]);
    float2 pd = *reinterpret_cast<const float2*>(&p[(size_t)d * 4 + 2]);
    float2 o;
    o.x = ps.x + pd.x + fcb[0];
    o.y = ps.y + pd.y + fcb[1];
    *reinterpret_cast<float2*>(&out[(size_t)e * 2]) = o;
}

// ---------------- launch ----------------

extern "C" void kernel_launch(void* const* d_in, const int* in_sizes, int n_in,
                              void* d_out, int out_size, void* d_ws, size_t ws_size,
                              hipStream_t stream) {
    const float* x   = (const float*)d_in[0];
    const float* rep = (const float*)d_in[1];
    const int*   src = (const int*)d_in[2];
    const int*   dst = (const int*)d_in[3];
    const float* W1  = (const float*)d_in[4];
    const float* al1 = (const float*)d_in[5];
    const float* ar1 = (const float*)d_in[6];
    const float* b1  = (const float*)d_in[7];
    const float* W2  = (const float*)d_in[8];
    const float* al2 = (const float*)d_in[9];
    const float* ar2 = (const float*)d_in[10];
    const float* b2  = (const float*)d_in[11];
    const float* fcW = (const float*)d_in[12];
    const float* fcb = (const float*)d_in[13];
    float* out = (float*)d_out;

    int N = in_sizes[0] / 64;   // 25000
    int E = in_sizes[2];        // 400000

    char* ws = (char*)d_ws;
    size_t off = 0;
    auto alloc = [&](size_t bytes) -> void* {
        void* ptr = ws + off;
        off = (off + bytes + 255) & ~(size_t)255;
        return ptr;
    };
    int*    deg     = (int*)alloc((size_t)N * 4);
    int*    row_ptr = (int*)alloc((size_t)(N + 1) * 4);
    int*    cursor  = (int*)alloc((size_t)N * 4);
    int*    csr_src = (int*)alloc((size_t)E * 4);
    float*  hbuf    = (float*)alloc((size_t)N * DH * 4);
    float*  gbuf    = (float*)alloc((size_t)N * DH * 4);
    float2* el2     = (float2*)alloc((size_t)N * 8);
    float2* er2     = (float2*)alloc((size_t)N * 8);
    float*  p       = (float*)alloc((size_t)N * 4 * 4);

    hipMemsetAsync(deg, 0, (size_t)N * 4, stream);

    int eb = (E + 255) / 256;
    int nb4 = (N + 3) / 4;
    k_degree<<<eb, 256, 0, stream>>>(dst, deg, E);
    k_scan<<<1, 1024, 0, stream>>>(deg, row_ptr, cursor, N);
    k_fill<<<eb, 256, 0, stream>>>(src, dst, cursor, csr_src, E);

    dim3 ggrid((N + BM - 1) / BM, DH / BN);
    // layer 1
    k_gemm<128, true><<<ggrid, 256, 0, stream>>>(x, rep, W1, hbuf, N);
    k_eler<<<nb4, 256, 0, stream>>>(hbuf, al1, ar1, el2, er2, N);
    k_agg<<<nb4, 256, 0, stream>>>(hbuf, el2, er2, row_ptr, csr_src, b1, gbuf, N);
    // layer 2
    k_gemm<256, false><<<ggrid, 256, 0, stream>>>(gbuf, nullptr, W2, hbuf, N);
    k_eler<<<nb4, 256, 0, stream>>>(hbuf, al2, ar2, el2, er2, N);
    k_agg<<<nb4, 256, 0, stream>>>(hbuf, el2, er2, row_ptr, csr_src, b2, gbuf, N);
    // classifier
    k_proj<<<(N * 64 + 255) / 256, 256, 0, stream>>>(gbuf, fcW, p, N);
    k_edgeout<<<eb, 256, 0, stream>>>(p, src, dst, fcb, out, E);
}

// Round 3
// 316.701 us; speedup vs baseline: 1.4515x; 1.2454x over previous
//
#include <hip/hip_runtime.h>
#include <hip/hip_bf16.h>

#define HEADS 2
#define HIDD  128
#define DH    256      // HEADS*HIDD
#define NEG   0.2f
#define CAP   128      // per-wave LDS edge cache

typedef _Float16 half4 __attribute__((ext_vector_type(4)));
typedef float    f32x4 __attribute__((ext_vector_type(4)));

// ---------------- CSR build ----------------

__global__ void k_degree(const int* __restrict__ dst, int* __restrict__ deg, int E) {
    int e = blockIdx.x * blockDim.x + threadIdx.x;
    if (e < E) atomicAdd(&deg[dst[e]], 1);
}

__global__ __launch_bounds__(1024) void k_scan(const int* __restrict__ deg,
                                               int* __restrict__ row_ptr,
                                               int* __restrict__ cursor, int n) {
    __shared__ int lds[1024];
    int tid = threadIdx.x;
    int base = tid * 32;
    int local[32];
    int sum = 0;
#pragma unroll
    for (int k = 0; k < 32; ++k) {
        int i = base + k;
        int v = (i < n) ? deg[i] : 0;
        local[k] = sum;
        sum += v;
    }
    lds[tid] = sum;
    __syncthreads();
    for (int off = 1; off < 1024; off <<= 1) {
        int t = (tid >= off) ? lds[tid - off] : 0;
        __syncthreads();
        lds[tid] += t;
        __syncthreads();
    }
    int thread_off = lds[tid] - sum;
#pragma unroll
    for (int k = 0; k < 32; ++k) {
        int i = base + k;
        if (i < n) {
            int rp = thread_off + local[k];
            row_ptr[i] = rp;
            cursor[i]  = rp;
        }
    }
    if (tid == 1023) row_ptr[n] = lds[1023];
}

__global__ void k_fill(const int* __restrict__ src, const int* __restrict__ dst,
                       int* __restrict__ cursor, int* __restrict__ csr_src, int E) {
    int e = blockIdx.x * blockDim.x + threadIdx.x;
    if (e < E) {
        int pos = atomicAdd(&cursor[dst[e]], 1);
        csr_src[pos] = src[e];
    }
}

// ---------------- cvt: feat->fp16, W1/W2 -> transposed fp16 ----------------

__global__ __launch_bounds__(256) void k_cvt(const float* __restrict__ x,
                                             const float* __restrict__ rep,
                                             const float* __restrict__ W1,
                                             const float* __restrict__ W2,
                                             _Float16* __restrict__ feat16,
                                             _Float16* __restrict__ W1T,
                                             _Float16* __restrict__ W2T, int N) {
    int gid = blockIdx.x * 256 + threadIdx.x;
    int featQuads = N * 32;                 // N*128/4
    if (gid < featQuads) {
        int n = gid >> 5, d = (gid & 31) * 4;
        const float* s = (d < 64) ? (x + (size_t)n * 64 + d) : (rep + (size_t)n * 64 + (d - 64));
        float4 v = *reinterpret_cast<const float4*>(s);
        half4 o = { (_Float16)v.x, (_Float16)v.y, (_Float16)v.z, (_Float16)v.w };
        *reinterpret_cast<half4*>(feat16 + (size_t)n * 128 + d) = o;
        return;
    }
    gid -= featQuads;
    if (gid < 256 * 128) {                  // W1T[n][k] = W1[k][n], K=128
        int n = gid >> 7, k = gid & 127;
        W1T[n * 128 + k] = (_Float16)W1[(size_t)k * 256 + n];
        return;
    }
    gid -= 256 * 128;
    if (gid < 256 * 256) {                  // W2T[n][k] = W2[k][n], K=256
        int n = gid >> 8, k = gid & 255;
        W2T[n * 256 + k] = (_Float16)W2[(size_t)k * 256 + n];
    }
}

// ---------------- MFMA GEMM: C16[M,256] = A16[M,K] @ (BT16[256,K])^T ----------------
// BM=64, BN=128, BK=64; 256 threads = 4 waves; wave -> 32 rows x 64 cols.
// mfma_f32_16x16x16_f16: A row=lane&15, k=4*(lane>>4)+j ; D col=lane&15, row=4*(lane>>4)+reg.
// LDS: k-contiguous rows of 64 f16 (128B), XOR-swizzled by ((row&7)<<4) bytes.

#define GBM 64
#define GBN 128
#define GBK 64

template<int K>
__global__ __launch_bounds__(256) void k_gemm16(const _Float16* __restrict__ A,
                                                const _Float16* __restrict__ BT,
                                                _Float16* __restrict__ C16, int M) {
    __shared__ _Float16 As[2][GBM * GBK];
    __shared__ _Float16 Bs[2][GBN * GBK];

    int tid = threadIdx.x;
    int lane = tid & 63;
    int wave = tid >> 6;
    int row0 = blockIdx.x * GBM;
    int col0 = blockIdx.y * GBN;
    int wrow = (wave & 1) * 32;
    int wcol = (wave >> 1) * 64;

    // staging registers
    uint4 ra[2], rb[4];
    const int am = tid >> 3;          // 0..31  (+32 for second chunk)
    const int ak8 = (tid & 7) * 8;    // k offset in elems

    auto stage_load = [&](int s) {
        const _Float16* ap = A + (size_t)(row0 + am) * K + s * GBK + ak8;
        ra[0] = *reinterpret_cast<const uint4*>(ap);
        ra[1] = *reinterpret_cast<const uint4*>(ap + (size_t)32 * K);
        const _Float16* bp = BT + (size_t)(col0 + am) * K + s * GBK + ak8;
#pragma unroll
        for (int it = 0; it < 4; ++it)
            rb[it] = *reinterpret_cast<const uint4*>(bp + (size_t)(it * 32) * K);
    };
    auto stage_write = [&](int buf) {
        char* ab = (char*)As[buf];
        char* bb = (char*)Bs[buf];
#pragma unroll
        for (int it = 0; it < 2; ++it) {
            int m = am + it * 32;
            int byte = (m * 128 + ak8 * 2) ^ ((m & 7) << 4);
            *reinterpret_cast<uint4*>(ab + byte) = ra[it];
        }
#pragma unroll
        for (int it = 0; it < 4; ++it) {
            int n = am + it * 32;
            int byte = (n * 128 + ak8 * 2) ^ ((n & 7) << 4);
            *reinterpret_cast<uint4*>(bb + byte) = rb[it];
        }
    };

    f32x4 acc[2][4];
#pragma unroll
    for (int i = 0; i < 2; ++i)
#pragma unroll
        for (int j = 0; j < 4; ++j) acc[i][j] = (f32x4){0.f, 0.f, 0.f, 0.f};

    stage_load(0);
    stage_write(0);
    __syncthreads();

    const int S = K / GBK;
    for (int s = 0; s < S; ++s) {
        if (s + 1 < S) stage_load(s + 1);
        // compute on buf s&1
        const char* ab = (const char*)As[s & 1];
        const char* bb = (const char*)Bs[s & 1];
#pragma unroll
        for (int kk = 0; kk < GBK / 16; ++kk) {
            half4 af[2], bf[4];
#pragma unroll
            for (int i = 0; i < 2; ++i) {
                int m = wrow + i * 16 + (lane & 15);
                int byte = (m * 128 + kk * 32 + (lane >> 4) * 8) ^ ((m & 7) << 4);
                af[i] = *reinterpret_cast<const half4*>(ab + byte);
            }
#pragma unroll
            for (int j = 0; j < 4; ++j) {
                int n = wcol + j * 16 + (lane & 15);
                int byte = (n * 128 + kk * 32 + (lane >> 4) * 8) ^ ((n & 7) << 4);
                bf[j] = *reinterpret_cast<const half4*>(bb + byte);
            }
#pragma unroll
            for (int i = 0; i < 2; ++i)
#pragma unroll
                for (int j = 0; j < 4; ++j)
                    acc[i][j] = __builtin_amdgcn_mfma_f32_16x16x16f16(af[i], bf[j], acc[i][j], 0, 0, 0);
        }
        if (s + 1 < S) stage_write((s + 1) & 1);
        __syncthreads();
    }

    // epilogue: fp16 store
    int r4 = (lane >> 4) * 4, cl = lane & 15;
#pragma unroll
    for (int i = 0; i < 2; ++i) {
#pragma unroll
        for (int r = 0; r < 4; ++r) {
            int row = row0 + wrow + i * 16 + r4 + r;
            if (row < M) {
                _Float16* cp = C16 + (size_t)row * DH + col0 + wcol + cl;
#pragma unroll
                for (int j = 0; j < 4; ++j)
                    cp[j * 16] = (_Float16)acc[i][j][r];
            }
        }
    }
}

// ---------------- el/er: per-node attention dots (wave per node, fp16 h) ----------------

__global__ __launch_bounds__(256) void k_eler(const _Float16* __restrict__ h,
                                              const float* __restrict__ al,
                                              const float* __restrict__ ar,
                                              float2* __restrict__ el2,
                                              float2* __restrict__ er2, int N) {
    int w = threadIdx.x >> 6, lane = threadIdx.x & 63;
    int node = blockIdx.x * 4 + w;
    if (node >= N) return;
    uint2 u = *reinterpret_cast<const uint2*>(h + (size_t)node * DH + lane * 4);
    const _Float16* hv = reinterpret_cast<const _Float16*>(&u);
    float4 a = *reinterpret_cast<const float4*>(al + lane * 4);
    float4 r = *reinterpret_cast<const float4*>(ar + lane * 4);
    float h0 = (float)hv[0], h1 = (float)hv[1], h2 = (float)hv[2], h3 = (float)hv[3];
    float sl = h0 * a.x + h1 * a.y + h2 * a.z + h3 * a.w;
    float sr = h0 * r.x + h1 * r.y + h2 * r.z + h3 * r.w;
#pragma unroll
    for (int off = 16; off; off >>= 1) {
        sl += __shfl_xor(sl, off);
        sr += __shfl_xor(sr, off);
    }
    float el0 = __shfl(sl, 0), el1 = __shfl(sl, 32);
    float er0 = __shfl(sr, 0), er1 = __shfl(sr, 32);
    if (lane == 0) el2[node] = make_float2(el0, el1);
    if (lane == 1) er2[node] = make_float2(er0, er1);
}

// ---------------- aggregation: wave-per-node softmax + fp16 gather ----------------

__global__ __launch_bounds__(256) void k_agg(const _Float16* __restrict__ h,
                                             const float2* __restrict__ el2,
                                             const float2* __restrict__ er2,
                                             const int* __restrict__ row_ptr,
                                             const int* __restrict__ csr_src,
                                             const float* __restrict__ bias,
                                             _Float16* __restrict__ g, int N) {
    __shared__ int    s_idx[4][CAP];
    __shared__ float2 s_a[4][CAP];

    int w = threadIdx.x >> 6, lane = threadIdx.x & 63;
    int node = blockIdx.x * 4 + w;
    if (node >= N) return;    // no block-wide syncs anywhere
    int beg = row_ptr[node];
    int deg = row_ptr[node + 1] - beg;
    float2 er = er2[node];
    bool lo = lane < 32;

    // phase 1: scores + wave max
    float m0 = -__builtin_inff(), m1 = -__builtin_inff();
    for (int i = lane; i < deg; i += 64) {
        int s = csr_src[beg + i];
        float2 el = el2[s];
        float sc0 = el.x + er.x; sc0 = sc0 > 0.f ? sc0 : NEG * sc0;
        float sc1 = el.y + er.y; sc1 = sc1 > 0.f ? sc1 : NEG * sc1;
        if (i < CAP) { s_idx[w][i] = s; s_a[w][i] = make_float2(sc0, sc1); }
        m0 = fmaxf(m0, sc0);
        m1 = fmaxf(m1, sc1);
    }
#pragma unroll
    for (int off = 32; off; off >>= 1) {
        m0 = fmaxf(m0, __shfl_xor(m0, off));
        m1 = fmaxf(m1, __shfl_xor(m1, off));
    }

    // phase 2: exp + wave sum
    float sum0 = 0.f, sum1 = 0.f;
    for (int i = lane; i < deg; i += 64) {
        float2 sc;
        if (i < CAP) sc = s_a[w][i];
        else {
            int s = csr_src[beg + i];
            float2 el = el2[s];
            sc.x = el.x + er.x; sc.x = sc.x > 0.f ? sc.x : NEG * sc.x;
            sc.y = el.y + er.y; sc.y = sc.y > 0.f ? sc.y : NEG * sc.y;
        }
        float e0 = __expf(sc.x - m0);
        float e1 = __expf(sc.y - m1);
        if (i < CAP) s_a[w][i] = make_float2(e0, e1);
        sum0 += e0;
        sum1 += e1;
    }
#pragma unroll
    for (int off = 32; off; off >>= 1) {
        sum0 += __shfl_xor(sum0, off);
        sum1 += __shfl_xor(sum1, off);
    }
    float S   = lo ? sum0 : sum1;
    float inv = S > 0.f ? 1.f / S : 0.f;
    float mh  = lo ? m0 : m1;
    float erh = lo ? er.x : er.y;

    // phase 3: fp16 gather (8B/lane/edge), 4 edges in flight
    const _Float16* hp = h + lane * 4;
    float4 acc = make_float4(0.f, 0.f, 0.f, 0.f);

#define FETCH(I, S_, A_)                                                    \
    do {                                                                     \
        int _i = (I);                                                        \
        if (_i < CAP) {                                                      \
            S_ = s_idx[w][_i];                                               \
            float2 _a2 = s_a[w][_i];                                         \
            A_ = lo ? _a2.x : _a2.y;                                         \
        } else {                                                             \
            S_ = csr_src[beg + _i];                                          \
            float2 _el = el2[S_];                                            \
            float _sc = (lo ? _el.x : _el.y) + erh;                          \
            _sc = _sc > 0.f ? _sc : NEG * _sc;                               \
            A_ = __expf(_sc - mh);                                           \
        }                                                                    \
    } while (0)

#define ACCUM(V, A_)                                                         \
    do {                                                                     \
        const _Float16* _hv = reinterpret_cast<const _Float16*>(&(V));       \
        acc.x = fmaf(A_, (float)_hv[0], acc.x);                              \
        acc.y = fmaf(A_, (float)_hv[1], acc.y);                              \
        acc.z = fmaf(A_, (float)_hv[2], acc.z);                              \
        acc.w = fmaf(A_, (float)_hv[3], acc.w);                              \
    } while (0)

    int i = 0;
    for (; i + 4 <= deg; i += 4) {
        int s0, s1, s2, s3;
        float a0, a1, a2, a3;
        FETCH(i,     s0, a0);
        FETCH(i + 1, s1, a1);
        FETCH(i + 2, s2, a2);
        FETCH(i + 3, s3, a3);
        uint2 v0 = *reinterpret_cast<const uint2*>(hp + (size_t)s0 * DH);
        uint2 v1 = *reinterpret_cast<const uint2*>(hp + (size_t)s1 * DH);
        uint2 v2 = *reinterpret_cast<const uint2*>(hp + (size_t)s2 * DH);
        uint2 v3 = *reinterpret_cast<const uint2*>(hp + (size_t)s3 * DH);
        ACCUM(v0, a0); ACCUM(v1, a1); ACCUM(v2, a2); ACCUM(v3, a3);
    }
    for (; i < deg; ++i) {
        int s;
        float a;
        FETCH(i, s, a);
        uint2 v = *reinterpret_cast<const uint2*>(hp + (size_t)s * DH);
        ACCUM(v, a);
    }
#undef FETCH
#undef ACCUM

    float4 b = *reinterpret_cast<const float4*>(bias + lane * 4);
    half4 o;
    o[0] = (_Float16)fmaxf(fmaf(acc.x, inv, b.x), 0.f);
    o[1] = (_Float16)fmaxf(fmaf(acc.y, inv, b.y), 0.f);
    o[2] = (_Float16)fmaxf(fmaf(acc.z, inv, b.z), 0.f);
    o[3] = (_Float16)fmaxf(fmaf(acc.w, inv, b.w), 0.f);
    *reinterpret_cast<half4*>(g + (size_t)node * DH + lane * 4) = o;
}

// ---------------- final classifier ----------------

__global__ __launch_bounds__(256) void k_proj(const _Float16* __restrict__ g2,
                                              const float* __restrict__ fcW,
                                              float* __restrict__ p, int n) {
    int gid = blockIdx.x * blockDim.x + threadIdx.x;
    int wid = gid >> 6;
    int lane = threadIdx.x & 63;
    if (wid >= n) return;
    uint2 u = *reinterpret_cast<const uint2*>(g2 + (size_t)wid * DH + lane * 4);
    const _Float16* hv = reinterpret_cast<const _Float16*>(&u);
    float a0 = 0.f, a1 = 0.f, a2 = 0.f, a3 = 0.f;
#pragma unroll
    for (int t = 0; t < 4; ++t) {
        int d = lane * 4 + t;
        float v = (float)hv[t];
        float2 wt = *reinterpret_cast<const float2*>(&fcW[d * 2]);
        float2 wb = *reinterpret_cast<const float2*>(&fcW[(DH + d) * 2]);
        a0 = fmaf(v, wt.x, a0);
        a1 = fmaf(v, wt.y, a1);
        a2 = fmaf(v, wb.x, a2);
        a3 = fmaf(v, wb.y, a3);
    }
#pragma unroll
    for (int off = 32; off; off >>= 1) {
        a0 += __shfl_xor(a0, off);
        a1 += __shfl_xor(a1, off);
        a2 += __shfl_xor(a2, off);
        a3 += __shfl_xor(a3, off);
    }
    if (lane == 0) {
        float4 v = make_float4(a0, a1, a2, a3);
        *reinterpret_cast<float4*>(&p[(size_t)wid * 4]) = v;
    }
}

__global__ void k_edgeout(const float* __restrict__ p,
                          const int* __restrict__ src,
                          const int* __restrict__ dst,
                          const float* __restrict__ fcb,
                          float* __restrict__ out, int E) {
    int e = blockIdx.x * blockDim.x + threadIdx.x;
    if (e >= E) return;
    int s = src[e], d = dst[e];
    float2 ps = *reinterpret_cast<const float2*>(&p[(size_t)s * 4]);
    float2 pd = *reinterpret_cast<const float2*>(&p[(size_t)d * 4 + 2]);
    float2 o;
    o.x = ps.x + pd.x + fcb[0];
    o.y = ps.y + pd.y + fcb[1];
    *reinterpret_cast<float2*>(&out[(size_t)e * 2]) = o;
}

// ---------------- launch ----------------

extern "C" void kernel_launch(void* const* d_in, const int* in_sizes, int n_in,
                              void* d_out, int out_size, void* d_ws, size_t ws_size,
                              hipStream_t stream) {
    const float* x   = (const float*)d_in[0];
    const float* rep = (const float*)d_in[1];
    const int*   src = (const int*)d_in[2];
    const int*   dst = (const int*)d_in[3];
    const float* W1  = (const float*)d_in[4];
    const float* al1 = (const float*)d_in[5];
    const float* ar1 = (const float*)d_in[6];
    const float* b1  = (const float*)d_in[7];
    const float* W2  = (const float*)d_in[8];
    const float* al2 = (const float*)d_in[9];
    const float* ar2 = (const float*)d_in[10];
    const float* b2  = (const float*)d_in[11];
    const float* fcW = (const float*)d_in[12];
    const float* fcb = (const float*)d_in[13];
    float* out = (float*)d_out;

    int N = in_sizes[0] / 64;   // 25000
    int E = in_sizes[2];        // 400000

    char* ws = (char*)d_ws;
    size_t off = 0;
    auto alloc = [&](size_t bytes) -> void* {
        void* ptr = ws + off;
        off = (off + bytes + 255) & ~(size_t)255;
        return ptr;
    };
    int*       deg     = (int*)alloc((size_t)N * 4);
    int*       row_ptr = (int*)alloc((size_t)(N + 1) * 4);
    int*       cursor  = (int*)alloc((size_t)N * 4);
    int*       csr_src = (int*)alloc((size_t)E * 4);
    _Float16*  feat16  = (_Float16*)alloc((size_t)N * 128 * 2);
    _Float16*  W1T     = (_Float16*)alloc((size_t)256 * 128 * 2);
    _Float16*  W2T     = (_Float16*)alloc((size_t)256 * 256 * 2);
    _Float16*  h16     = (_Float16*)alloc((size_t)N * DH * 2);
    _Float16*  g16     = (_Float16*)alloc((size_t)N * DH * 2);
    float2*    el2     = (float2*)alloc((size_t)N * 8);
    float2*    er2     = (float2*)alloc((size_t)N * 8);
    float*     p       = (float*)alloc((size_t)N * 4 * 4);
    (void)alloc(65536);   // tail slack: gemm stage reads up to 63 rows past M

    hipMemsetAsync(deg, 0, (size_t)N * 4, stream);

    int eb = (E + 255) / 256;
    int nb4 = (N + 3) / 4;
    int cvt_blocks = (N * 32 + 256 * 128 + 256 * 256 + 255) / 256;

    k_cvt<<<cvt_blocks, 256, 0, stream>>>(x, rep, W1, W2, feat16, W1T, W2T, N);
    k_degree<<<eb, 256, 0, stream>>>(dst, deg, E);
    k_scan<<<1, 1024, 0, stream>>>(deg, row_ptr, cursor, N);
    k_fill<<<eb, 256, 0, stream>>>(src, dst, cursor, csr_src, E);

    dim3 ggrid((N + GBM - 1) / GBM, DH / GBN);
    // layer 1
    k_gemm16<128><<<ggrid, 256, 0, stream>>>(feat16, W1T, h16, N);
    k_eler<<<nb4, 256, 0, stream>>>(h16, al1, ar1, el2, er2, N);
    k_agg<<<nb4, 256, 0, stream>>>(h16, el2, er2, row_ptr, csr_src, b1, g16, N);
    // layer 2
    k_gemm16<256><<<ggrid, 256, 0, stream>>>(g16, W2T, h16, N);
    k_eler<<<nb4, 256, 0, stream>>>(h16, al2, ar2, el2, er2, N);
    k_agg<<<nb4, 256, 0, stream>>>(h16, el2, er2, row_ptr, csr_src, b2, g16, N);
    // classifier
    k_proj<<<(N * 64 + 255) / 256, 256, 0, stream>>>(g16, fcW, p, N);
    k_edgeout<<<eb, 256, 0, stream>>>(p, src, dst, fcb, out, E);
}

// Round 4
// 305.300 us; speedup vs baseline: 1.5057x; 1.0373x over previous
//
#include <hip/hip_runtime.h>
#include <hip/hip_bf16.h>

#define HEADS 2
#define HIDD  128
#define DH    256      // HEADS*HIDD
#define NEG   0.2f
#define CAP   128      // per-wave LDS edge cache

typedef _Float16 half4 __attribute__((ext_vector_type(4)));
typedef float    f32x4 __attribute__((ext_vector_type(4)));

// ---------------- prep: feat->fp16, W1/W2 -> transposed fp16, degree count ----------------

__global__ __launch_bounds__(256) void k_prep(const float* __restrict__ x,
                                              const float* __restrict__ rep,
                                              const float* __restrict__ W1,
                                              const float* __restrict__ W2,
                                              const int* __restrict__ dst,
                                              _Float16* __restrict__ feat16,
                                              _Float16* __restrict__ W1T,
                                              _Float16* __restrict__ W2T,
                                              int* __restrict__ deg,
                                              int N, int E) {
    int gid = blockIdx.x * 256 + threadIdx.x;
    int featQuads = N * 32;                 // N*128/4
    if (gid < featQuads) {
        int n = gid >> 5, d = (gid & 31) * 4;
        const float* s = (d < 64) ? (x + (size_t)n * 64 + d) : (rep + (size_t)n * 64 + (d - 64));
        float4 v = *reinterpret_cast<const float4*>(s);
        half4 o = { (_Float16)v.x, (_Float16)v.y, (_Float16)v.z, (_Float16)v.w };
        *reinterpret_cast<half4*>(feat16 + (size_t)n * 128 + d) = o;
        return;
    }
    gid -= featQuads;
    if (gid < 256 * 128) {                  // W1T[n][k] = W1[k][n], K=128
        int n = gid >> 7, k = gid & 127;
        W1T[n * 128 + k] = (_Float16)W1[(size_t)k * 256 + n];
        return;
    }
    gid -= 256 * 128;
    if (gid < 256 * 256) {                  // W2T[n][k] = W2[k][n], K=256
        int n = gid >> 8, k = gid & 255;
        W2T[n * 256 + k] = (_Float16)W2[(size_t)k * 256 + n];
        return;
    }
    gid -= 256 * 256;
    if (gid < E) atomicAdd(&deg[dst[gid]], 1);
}

// ---------------- scan (single block, int4 loads over zero-padded 32768 ints) ----------------

__global__ __launch_bounds__(1024) void k_scan(const int* __restrict__ deg,
                                               int* __restrict__ row_ptr,
                                               int* __restrict__ cursor, int n) {
    __shared__ int lds[1024];
    int tid = threadIdx.x;
    int base = tid * 32;
    int v[32];
#pragma unroll
    for (int k = 0; k < 8; ++k) {
        int4 q = *reinterpret_cast<const int4*>(deg + base + k * 4);
        v[k * 4 + 0] = q.x; v[k * 4 + 1] = q.y; v[k * 4 + 2] = q.z; v[k * 4 + 3] = q.w;
    }
    int local[32];
    int sum = 0;
#pragma unroll
    for (int k = 0; k < 32; ++k) { local[k] = sum; sum += v[k]; }
    lds[tid] = sum;
    __syncthreads();
    for (int off = 1; off < 1024; off <<= 1) {
        int t = (tid >= off) ? lds[tid - off] : 0;
        __syncthreads();
        lds[tid] += t;
        __syncthreads();
    }
    int thread_off = lds[tid] - sum;
#pragma unroll
    for (int k = 0; k < 32; ++k) {
        int i = base + k;
        if (i < n) {
            int rp = thread_off + local[k];
            row_ptr[i] = rp;
            cursor[i]  = rp;
        }
    }
    if (tid == 1023) row_ptr[n] = lds[1023];
}

__global__ void k_fill(const int* __restrict__ src, const int* __restrict__ dst,
                       int* __restrict__ cursor, int* __restrict__ csr_src, int E) {
    int e = blockIdx.x * blockDim.x + threadIdx.x;
    if (e < E) {
        int pos = atomicAdd(&cursor[dst[e]], 1);
        csr_src[pos] = src[e];
    }
}

// ---------------- MFMA GEMM + fused el/er ----------------
// C16[M,256] = A16[M,K] @ (BT16[256,K])^T ; BM=64, BN=128 (= one head), BK=64.
// 256 threads = 4 waves; wave -> 32 rows x 64 cols.
// mfma_f32_16x16x16_f16: A row=lane&15, k=4*(lane>>4)+j ; D col=lane&15, row=4*(lane>>4)+reg.
// Epilogue: stage C tile in LDS (reusing As), coalesced 16B stores, then per-row
// dot with al/ar slice for THIS block's 128 cols = one complete head component.

#define GBM 64
#define GBN 128
#define GBK 64

template<int K>
__global__ __launch_bounds__(256) void k_gemm16(const _Float16* __restrict__ A,
                                                const _Float16* __restrict__ BT,
                                                _Float16* __restrict__ C16,
                                                const float* __restrict__ alp,
                                                const float* __restrict__ arp,
                                                float* __restrict__ el,
                                                float* __restrict__ er, int M) {
    __shared__ _Float16 As[2][GBM * GBK];   // 16KB total (reused as C-stage)
    __shared__ _Float16 Bs[2][GBN * GBK];   // 32KB

    int tid = threadIdx.x;
    int lane = tid & 63;
    int wave = tid >> 6;
    int row0 = blockIdx.x * GBM;
    int col0 = blockIdx.y * GBN;
    int wrow = (wave & 1) * 32;
    int wcol = (wave >> 1) * 64;

    uint4 ra[2], rb[4];
    const int am = tid >> 3;          // 0..31 (+32 for second chunk)
    const int ak8 = (tid & 7) * 8;    // k offset in elems

    auto stage_load = [&](int s) {
        const _Float16* ap = A + (size_t)(row0 + am) * K + s * GBK + ak8;
        ra[0] = *reinterpret_cast<const uint4*>(ap);
        ra[1] = *reinterpret_cast<const uint4*>(ap + (size_t)32 * K);
        const _Float16* bp = BT + (size_t)(col0 + am) * K + s * GBK + ak8;
#pragma unroll
        for (int it = 0; it < 4; ++it)
            rb[it] = *reinterpret_cast<const uint4*>(bp + (size_t)(it * 32) * K);
    };
    auto stage_write = [&](int buf) {
        char* ab = (char*)As[buf];
        char* bb = (char*)Bs[buf];
#pragma unroll
        for (int it = 0; it < 2; ++it) {
            int m = am + it * 32;
            int byte = (m * 128 + ak8 * 2) ^ ((m & 7) << 4);
            *reinterpret_cast<uint4*>(ab + byte) = ra[it];
        }
#pragma unroll
        for (int it = 0; it < 4; ++it) {
            int n = am + it * 32;
            int byte = (n * 128 + ak8 * 2) ^ ((n & 7) << 4);
            *reinterpret_cast<uint4*>(bb + byte) = rb[it];
        }
    };

    f32x4 acc[2][4];
#pragma unroll
    for (int i = 0; i < 2; ++i)
#pragma unroll
        for (int j = 0; j < 4; ++j) acc[i][j] = (f32x4){0.f, 0.f, 0.f, 0.f};

    stage_load(0);
    stage_write(0);
    __syncthreads();

    const int S = K / GBK;
    for (int s = 0; s < S; ++s) {
        if (s + 1 < S) stage_load(s + 1);
        const char* ab = (const char*)As[s & 1];
        const char* bb = (const char*)Bs[s & 1];
#pragma unroll
        for (int kk = 0; kk < GBK / 16; ++kk) {
            half4 af[2], bf[4];
#pragma unroll
            for (int i = 0; i < 2; ++i) {
                int m = wrow + i * 16 + (lane & 15);
                int byte = (m * 128 + kk * 32 + (lane >> 4) * 8) ^ ((m & 7) << 4);
                af[i] = *reinterpret_cast<const half4*>(ab + byte);
            }
#pragma unroll
            for (int j = 0; j < 4; ++j) {
                int n = wcol + j * 16 + (lane & 15);
                int byte = (n * 128 + kk * 32 + (lane >> 4) * 8) ^ ((n & 7) << 4);
                bf[j] = *reinterpret_cast<const half4*>(bb + byte);
            }
#pragma unroll
            for (int i = 0; i < 2; ++i)
#pragma unroll
                for (int j = 0; j < 4; ++j)
                    acc[i][j] = __builtin_amdgcn_mfma_f32_16x16x16f16(af[i], bf[j], acc[i][j], 0, 0, 0);
        }
        if (s + 1 < S) stage_write((s + 1) & 1);
        __syncthreads();
    }

    // ---- epilogue: scatter accs into LDS C tile (swizzled), then coalesced IO ----
    char* Cs = (char*)As;                     // 64 rows x 256B = 16KB
    {
        int r4 = (lane >> 4) * 4, cl = lane & 15;
#pragma unroll
        for (int i = 0; i < 2; ++i)
#pragma unroll
            for (int j = 0; j < 4; ++j) {
                int col = wcol + j * 16 + cl;
#pragma unroll
                for (int r = 0; r < 4; ++r) {
                    int row = wrow + i * 16 + r4 + r;
                    int byte = (row * 256 + col * 2) ^ ((row & 7) << 4);
                    *reinterpret_cast<_Float16*>(Cs + byte) = (_Float16)acc[i][j][r];
                }
            }
    }
    __syncthreads();

    // coalesced 16B stores of the tile
#pragma unroll
    for (int it = 0; it < 4; ++it) {
        int lin = tid + it * 256;
        int row = lin >> 4, chunk = lin & 15;
        int gr = row0 + row;
        if (gr < M) {
            int byte = (row * 256 + chunk * 16) ^ ((row & 7) << 4);
            *reinterpret_cast<uint4*>(C16 + (size_t)gr * DH + col0 + chunk * 8) =
                *reinterpret_cast<const uint4*>(Cs + byte);
        }
    }

    // fused el/er: this block's 128 cols are one full head component
    {
        int r = lane >> 2, q = lane & 3;      // wave handles 16 rows, 4 lanes per row
        int row = wave * 16 + r;
        const float* alg = alp + col0;
        const float* arg = arp + col0;
        float els = 0.f, ers = 0.f;
#pragma unroll
        for (int kk = 0; kk < 4; ++kk) {
            int c0 = q * 32 + kk * 8;
            int byte = (row * 256 + c0 * 2) ^ ((row & 7) << 4);
            uint4 u = *reinterpret_cast<const uint4*>(Cs + byte);
            const _Float16* hv = (const _Float16*)&u;
#pragma unroll
            for (int t = 0; t < 8; ++t) {
                float hvv = (float)hv[t];
                els = fmaf(hvv, alg[c0 + t], els);
                ers = fmaf(hvv, arg[c0 + t], ers);
            }
        }
        els += __shfl_xor(els, 1); els += __shfl_xor(els, 2);
        ers += __shfl_xor(ers, 1); ers += __shfl_xor(ers, 2);
        int gr = row0 + row;
        if (q == 0 && gr < M) {
            el[gr * 2 + blockIdx.y] = els;
            er[gr * 2 + blockIdx.y] = ers;
        }
    }
}

// ---------------- aggregation: wave-per-node softmax + fp16 gather ----------------

__global__ __launch_bounds__(256) void k_agg(const _Float16* __restrict__ h,
                                             const float2* __restrict__ el2,
                                             const float2* __restrict__ er2,
                                             const int* __restrict__ row_ptr,
                                             const int* __restrict__ csr_src,
                                             const float* __restrict__ bias,
                                             _Float16* __restrict__ g, int N) {
    __shared__ int    s_idx[4][CAP];
    __shared__ float2 s_a[4][CAP];

    int w = threadIdx.x >> 6, lane = threadIdx.x & 63;
    int node = blockIdx.x * 4 + w;
    if (node >= N) return;    // no block-wide syncs anywhere
    int beg = row_ptr[node];
    int deg = row_ptr[node + 1] - beg;
    float2 er = er2[node];
    bool lo = lane < 32;

    // phase 1: scores + wave max
    float m0 = -__builtin_inff(), m1 = -__builtin_inff();
    for (int i = lane; i < deg; i += 64) {
        int s = csr_src[beg + i];
        float2 el = el2[s];
        float sc0 = el.x + er.x; sc0 = sc0 > 0.f ? sc0 : NEG * sc0;
        float sc1 = el.y + er.y; sc1 = sc1 > 0.f ? sc1 : NEG * sc1;
        if (i < CAP) { s_idx[w][i] = s; s_a[w][i] = make_float2(sc0, sc1); }
        m0 = fmaxf(m0, sc0);
        m1 = fmaxf(m1, sc1);
    }
#pragma unroll
    for (int off = 32; off; off >>= 1) {
        m0 = fmaxf(m0, __shfl_xor(m0, off));
        m1 = fmaxf(m1, __shfl_xor(m1, off));
    }

    // phase 2: exp + wave sum
    float sum0 = 0.f, sum1 = 0.f;
    for (int i = lane; i < deg; i += 64) {
        float2 sc;
        if (i < CAP) sc = s_a[w][i];
        else {
            int s = csr_src[beg + i];
            float2 el = el2[s];
            sc.x = el.x + er.x; sc.x = sc.x > 0.f ? sc.x : NEG * sc.x;
            sc.y = el.y + er.y; sc.y = sc.y > 0.f ? sc.y : NEG * sc.y;
        }
        float e0 = __expf(sc.x - m0);
        float e1 = __expf(sc.y - m1);
        if (i < CAP) s_a[w][i] = make_float2(e0, e1);
        sum0 += e0;
        sum1 += e1;
    }
#pragma unroll
    for (int off = 32; off; off >>= 1) {
        sum0 += __shfl_xor(sum0, off);
        sum1 += __shfl_xor(sum1, off);
    }
    float S   = lo ? sum0 : sum1;
    float inv = S > 0.f ? 1.f / S : 0.f;
    float mh  = lo ? m0 : m1;
    float erh = lo ? er.x : er.y;

    // phase 3: fp16 gather (8B/lane/edge), 4 edges in flight
    const _Float16* hp = h + lane * 4;
    float4 acc = make_float4(0.f, 0.f, 0.f, 0.f);

#define FETCH(I, S_, A_)                                                    \
    do {                                                                     \
        int _i = (I);                                                        \
        if (_i < CAP) {                                                      \
            S_ = s_idx[w][_i];                                               \
            float2 _a2 = s_a[w][_i];                                         \
            A_ = lo ? _a2.x : _a2.y;                                         \
        } else {                                                             \
            S_ = csr_src[beg + _i];                                          \
            float2 _el = el2[S_];                                            \
            float _sc = (lo ? _el.x : _el.y) + erh;                          \
            _sc = _sc > 0.f ? _sc : NEG * _sc;                               \
            A_ = __expf(_sc - mh);                                           \
        }                                                                    \
    } while (0)

#define ACCUM(V, A_)                                                         \
    do {                                                                     \
        const _Float16* _hv = reinterpret_cast<const _Float16*>(&(V));       \
        acc.x = fmaf(A_, (float)_hv[0], acc.x);                              \
        acc.y = fmaf(A_, (float)_hv[1], acc.y);                              \
        acc.z = fmaf(A_, (float)_hv[2], acc.z);                              \
        acc.w = fmaf(A_, (float)_hv[3], acc.w);                              \
    } while (0)

    int i = 0;
    for (; i + 4 <= deg; i += 4) {
        int s0, s1, s2, s3;
        float a0, a1, a2, a3;
        FETCH(i,     s0, a0);
        FETCH(i + 1, s1, a1);
        FETCH(i + 2, s2, a2);
        FETCH(i + 3, s3, a3);
        uint2 v0 = *reinterpret_cast<const uint2*>(hp + (size_t)s0 * DH);
        uint2 v1 = *reinterpret_cast<const uint2*>(hp + (size_t)s1 * DH);
        uint2 v2 = *reinterpret_cast<const uint2*>(hp + (size_t)s2 * DH);
        uint2 v3 = *reinterpret_cast<const uint2*>(hp + (size_t)s3 * DH);
        ACCUM(v0, a0); ACCUM(v1, a1); ACCUM(v2, a2); ACCUM(v3, a3);
    }
    for (; i < deg; ++i) {
        int s;
        float a;
        FETCH(i, s, a);
        uint2 v = *reinterpret_cast<const uint2*>(hp + (size_t)s * DH);
        ACCUM(v, a);
    }
#undef FETCH
#undef ACCUM

    float4 b = *reinterpret_cast<const float4*>(bias + lane * 4);
    half4 o;
    o[0] = (_Float16)fmaxf(fmaf(acc.x, inv, b.x), 0.f);
    o[1] = (_Float16)fmaxf(fmaf(acc.y, inv, b.y), 0.f);
    o[2] = (_Float16)fmaxf(fmaf(acc.z, inv, b.z), 0.f);
    o[3] = (_Float16)fmaxf(fmaf(acc.w, inv, b.w), 0.f);
    *reinterpret_cast<half4*>(g + (size_t)node * DH + lane * 4) = o;
}

// ---------------- final classifier ----------------

__global__ __launch_bounds__(256) void k_proj(const _Float16* __restrict__ g2,
                                              const float* __restrict__ fcW,
                                              float* __restrict__ p, int n) {
    int gid = blockIdx.x * blockDim.x + threadIdx.x;
    int wid = gid >> 6;
    int lane = threadIdx.x & 63;
    if (wid >= n) return;
    uint2 u = *reinterpret_cast<const uint2*>(g2 + (size_t)wid * DH + lane * 4);
    const _Float16* hv = reinterpret_cast<const _Float16*>(&u);
    float a0 = 0.f, a1 = 0.f, a2 = 0.f, a3 = 0.f;
#pragma unroll
    for (int t = 0; t < 4; ++t) {
        int d = lane * 4 + t;
        float v = (float)hv[t];
        float2 wt = *reinterpret_cast<const float2*>(&fcW[d * 2]);
        float2 wb = *reinterpret_cast<const float2*>(&fcW[(DH + d) * 2]);
        a0 = fmaf(v, wt.x, a0);
        a1 = fmaf(v, wt.y, a1);
        a2 = fmaf(v, wb.x, a2);
        a3 = fmaf(v, wb.y, a3);
    }
#pragma unroll
    for (int off = 32; off; off >>= 1) {
        a0 += __shfl_xor(a0, off);
        a1 += __shfl_xor(a1, off);
        a2 += __shfl_xor(a2, off);
        a3 += __shfl_xor(a3, off);
    }
    if (lane == 0) {
        float4 v = make_float4(a0, a1, a2, a3);
        *reinterpret_cast<float4*>(&p[(size_t)wid * 4]) = v;
    }
}

__global__ void k_edgeout(const float* __restrict__ p,
                          const int* __restrict__ src,
                          const int* __restrict__ dst,
                          const float* __restrict__ fcb,
                          float* __restrict__ out, int E) {
    int e = blockIdx.x * blockDim.x + threadIdx.x;
    if (e >= E) return;
    int s = src[e], d = dst[e];
    float2 ps = *reinterpret_cast<const float2*>(&p[(size_t)s * 4]);
    float2 pd = *reinterpret_cast<const float2*>(&p[(size_t)d * 4 + 2]);
    float2 o;
    o.x = ps.x + pd.x + fcb[0];
    o.y = ps.y + pd.y + fcb[1];
    *reinterpret_cast<float2*>(&out[(size_t)e * 2]) = o;
}

// ---------------- launch ----------------

extern "C" void kernel_launch(void* const* d_in, const int* in_sizes, int n_in,
                              void* d_out, int out_size, void* d_ws, size_t ws_size,
                              hipStream_t stream) {
    const float* x   = (const float*)d_in[0];
    const float* rep = (const float*)d_in[1];
    const int*   src = (const int*)d_in[2];
    const int*   dst = (const int*)d_in[3];
    const float* W1  = (const float*)d_in[4];
    const float* al1 = (const float*)d_in[5];
    const float* ar1 = (const float*)d_in[6];
    const float* b1  = (const float*)d_in[7];
    const float* W2  = (const float*)d_in[8];
    const float* al2 = (const float*)d_in[9];
    const float* ar2 = (const float*)d_in[10];
    const float* b2  = (const float*)d_in[11];
    const float* fcW = (const float*)d_in[12];
    const float* fcb = (const float*)d_in[13];
    float* out = (float*)d_out;

    int N = in_sizes[0] / 64;   // 25000
    int E = in_sizes[2];        // 400000

    char* ws = (char*)d_ws;
    size_t off = 0;
    auto alloc = [&](size_t bytes) -> void* {
        void* ptr = ws + off;
        off = (off + bytes + 255) & ~(size_t)255;
        return ptr;
    };
    int*       deg     = (int*)alloc((size_t)32768 * 4);    // zero-padded for vector scan
    int*       row_ptr = (int*)alloc((size_t)(N + 1) * 4);
    int*       cursor  = (int*)alloc((size_t)N * 4);
    int*       csr_src = (int*)alloc((size_t)E * 4);
    _Float16*  feat16  = (_Float16*)alloc((size_t)N * 128 * 2);
    _Float16*  W1T     = (_Float16*)alloc((size_t)256 * 128 * 2);
    _Float16*  W2T     = (_Float16*)alloc((size_t)256 * 256 * 2);
    _Float16*  h16     = (_Float16*)alloc((size_t)N * DH * 2);
    _Float16*  g16     = (_Float16*)alloc((size_t)N * DH * 2);
    float*     el      = (float*)alloc((size_t)N * 2 * 4);
    float*     er      = (float*)alloc((size_t)N * 2 * 4);
    float*     p       = (float*)alloc((size_t)N * 4 * 4);
    (void)alloc(65536);   // tail slack: gemm stage reads up to 63 rows past M

    hipMemsetAsync(deg, 0, (size_t)32768 * 4, stream);

    int eb = (E + 255) / 256;
    int nb4 = (N + 3) / 4;
    int prep_blocks = (N * 32 + 256 * 128 + 256 * 256 + E + 255) / 256;

    k_prep<<<prep_blocks, 256, 0, stream>>>(x, rep, W1, W2, dst, feat16, W1T, W2T, deg, N, E);
    k_scan<<<1, 1024, 0, stream>>>(deg, row_ptr, cursor, N);
    k_fill<<<eb, 256, 0, stream>>>(src, dst, cursor, csr_src, E);

    dim3 ggrid((N + GBM - 1) / GBM, DH / GBN);
    // layer 1 (gemm writes h16 AND el/er)
    k_gemm16<128><<<ggrid, 256, 0, stream>>>(feat16, W1T, h16, al1, ar1, el, er, N);
    k_agg<<<nb4, 256, 0, stream>>>(h16, (const float2*)el, (const float2*)er, row_ptr, csr_src, b1, g16, N);
    // layer 2
    k_gemm16<256><<<ggrid, 256, 0, stream>>>(g16, W2T, h16, al2, ar2, el, er, N);
    k_agg<<<nb4, 256, 0, stream>>>(h16, (const float2*)el, (const float2*)er, row_ptr, csr_src, b2, g16, N);
    // classifier
    k_proj<<<(N * 64 + 255) / 256, 256, 0, stream>>>(g16, fcW, p, N);
    k_edgeout<<<eb, 256, 0, stream>>>(p, src, dst, fcb, out, E);
}

// Round 5
// 298.319 us; speedup vs baseline: 1.5409x; 1.0234x over previous
//
#include <hip/hip_runtime.h>
#include <hip/hip_bf16.h>

#define HEADS 2
#define HIDD  128
#define DH    256      // HEADS*HIDD
#define NEG   0.2f
#define CAP   128      // per-wave LDS edge cache

typedef _Float16 half4 __attribute__((ext_vector_type(4)));
typedef float    f32x4 __attribute__((ext_vector_type(4)));

// ---------------- prep: feat->fp16, W1/W2 -> transposed fp16, degree count ----------------

__global__ __launch_bounds__(256) void k_prep(const float* __restrict__ x,
                                              const float* __restrict__ rep,
                                              const float* __restrict__ W1,
                                              const float* __restrict__ W2,
                                              const int* __restrict__ dst,
                                              _Float16* __restrict__ feat16,
                                              _Float16* __restrict__ W1T,
                                              _Float16* __restrict__ W2T,
                                              int* __restrict__ deg,
                                              int N, int E) {
    int gid = blockIdx.x * 256 + threadIdx.x;
    int featQuads = N * 32;                 // N*128/4
    if (gid < featQuads) {
        int n = gid >> 5, d = (gid & 31) * 4;
        const float* s = (d < 64) ? (x + (size_t)n * 64 + d) : (rep + (size_t)n * 64 + (d - 64));
        float4 v = *reinterpret_cast<const float4*>(s);
        half4 o = { (_Float16)v.x, (_Float16)v.y, (_Float16)v.z, (_Float16)v.w };
        *reinterpret_cast<half4*>(feat16 + (size_t)n * 128 + d) = o;
        return;
    }
    gid -= featQuads;
    if (gid < 256 * 128) {                  // W1T[n][k] = W1[k][n], K=128
        int n = gid >> 7, k = gid & 127;
        W1T[n * 128 + k] = (_Float16)W1[(size_t)k * 256 + n];
        return;
    }
    gid -= 256 * 128;
    if (gid < 256 * 256) {                  // W2T[n][k] = W2[k][n], K=256
        int n = gid >> 8, k = gid & 255;
        W2T[n * 256 + k] = (_Float16)W2[(size_t)k * 256 + n];
        return;
    }
    gid -= 256 * 256;
    if (gid < E) atomicAdd(&deg[dst[gid]], 1);
}

// ---------------- scan (single block, int4 loads over zero-padded 32768 ints) ----------------

__global__ __launch_bounds__(1024) void k_scan(const int* __restrict__ deg,
                                               int* __restrict__ row_ptr,
                                               int* __restrict__ cursor, int n) {
    __shared__ int lds[1024];
    int tid = threadIdx.x;
    int base = tid * 32;
    int v[32];
#pragma unroll
    for (int k = 0; k < 8; ++k) {
        int4 q = *reinterpret_cast<const int4*>(deg + base + k * 4);
        v[k * 4 + 0] = q.x; v[k * 4 + 1] = q.y; v[k * 4 + 2] = q.z; v[k * 4 + 3] = q.w;
    }
    int local[32];
    int sum = 0;
#pragma unroll
    for (int k = 0; k < 32; ++k) { local[k] = sum; sum += v[k]; }
    lds[tid] = sum;
    __syncthreads();
    for (int off = 1; off < 1024; off <<= 1) {
        int t = (tid >= off) ? lds[tid - off] : 0;
        __syncthreads();
        lds[tid] += t;
        __syncthreads();
    }
    int thread_off = lds[tid] - sum;
#pragma unroll
    for (int k = 0; k < 32; ++k) {
        int i = base + k;
        if (i < n) {
            int rp = thread_off + local[k];
            row_ptr[i] = rp;
            cursor[i]  = rp;
        }
    }
    if (tid == 1023) row_ptr[n] = lds[1023];
}

__global__ void k_fill(const int* __restrict__ src, const int* __restrict__ dst,
                       int* __restrict__ cursor, int* __restrict__ csr_src, int E) {
    int e = blockIdx.x * blockDim.x + threadIdx.x;
    if (e < E) {
        int pos = atomicAdd(&cursor[dst[e]], 1);
        csr_src[pos] = src[e];
    }
}

// ---------------- MFMA GEMM + fused el/er ----------------
// C16[M,256] = A16[M,K] @ (BT16[256,K])^T ; BM=64, BN=128 (= one head), BK=64.

#define GBM 64
#define GBN 128
#define GBK 64

template<int K>
__global__ __launch_bounds__(256) void k_gemm16(const _Float16* __restrict__ A,
                                                const _Float16* __restrict__ BT,
                                                _Float16* __restrict__ C16,
                                                const float* __restrict__ alp,
                                                const float* __restrict__ arp,
                                                float* __restrict__ el,
                                                float* __restrict__ er, int M) {
    __shared__ _Float16 As[2][GBM * GBK];   // 16KB (reused as C-stage)
    __shared__ _Float16 Bs[2][GBN * GBK];   // 32KB

    int tid = threadIdx.x;
    int lane = tid & 63;
    int wave = tid >> 6;
    int row0 = blockIdx.x * GBM;
    int col0 = blockIdx.y * GBN;
    int wrow = (wave & 1) * 32;
    int wcol = (wave >> 1) * 64;

    uint4 ra[2], rb[4];
    const int am = tid >> 3;
    const int ak8 = (tid & 7) * 8;

    auto stage_load = [&](int s) {
        const _Float16* ap = A + (size_t)(row0 + am) * K + s * GBK + ak8;
        ra[0] = *reinterpret_cast<const uint4*>(ap);
        ra[1] = *reinterpret_cast<const uint4*>(ap + (size_t)32 * K);
        const _Float16* bp = BT + (size_t)(col0 + am) * K + s * GBK + ak8;
#pragma unroll
        for (int it = 0; it < 4; ++it)
            rb[it] = *reinterpret_cast<const uint4*>(bp + (size_t)(it * 32) * K);
    };
    auto stage_write = [&](int buf) {
        char* ab = (char*)As[buf];
        char* bb = (char*)Bs[buf];
#pragma unroll
        for (int it = 0; it < 2; ++it) {
            int m = am + it * 32;
            int byte = (m * 128 + ak8 * 2) ^ ((m & 7) << 4);
            *reinterpret_cast<uint4*>(ab + byte) = ra[it];
        }
#pragma unroll
        for (int it = 0; it < 4; ++it) {
            int n = am + it * 32;
            int byte = (n * 128 + ak8 * 2) ^ ((n & 7) << 4);
            *reinterpret_cast<uint4*>(bb + byte) = rb[it];
        }
    };

    f32x4 acc[2][4];
#pragma unroll
    for (int i = 0; i < 2; ++i)
#pragma unroll
        for (int j = 0; j < 4; ++j) acc[i][j] = (f32x4){0.f, 0.f, 0.f, 0.f};

    stage_load(0);
    stage_write(0);
    __syncthreads();

    const int S = K / GBK;
    for (int s = 0; s < S; ++s) {
        if (s + 1 < S) stage_load(s + 1);
        const char* ab = (const char*)As[s & 1];
        const char* bb = (const char*)Bs[s & 1];
#pragma unroll
        for (int kk = 0; kk < GBK / 16; ++kk) {
            half4 af[2], bf[4];
#pragma unroll
            for (int i = 0; i < 2; ++i) {
                int m = wrow + i * 16 + (lane & 15);
                int byte = (m * 128 + kk * 32 + (lane >> 4) * 8) ^ ((m & 7) << 4);
                af[i] = *reinterpret_cast<const half4*>(ab + byte);
            }
#pragma unroll
            for (int j = 0; j < 4; ++j) {
                int n = wcol + j * 16 + (lane & 15);
                int byte = (n * 128 + kk * 32 + (lane >> 4) * 8) ^ ((n & 7) << 4);
                bf[j] = *reinterpret_cast<const half4*>(bb + byte);
            }
#pragma unroll
            for (int i = 0; i < 2; ++i)
#pragma unroll
                for (int j = 0; j < 4; ++j)
                    acc[i][j] = __builtin_amdgcn_mfma_f32_16x16x16f16(af[i], bf[j], acc[i][j], 0, 0, 0);
        }
        if (s + 1 < S) stage_write((s + 1) & 1);
        __syncthreads();
    }

    // ---- epilogue: scatter accs into LDS C tile (swizzled), then coalesced IO ----
    char* Cs = (char*)As;                     // 64 rows x 256B = 16KB
    {
        int r4 = (lane >> 4) * 4, cl = lane & 15;
#pragma unroll
        for (int i = 0; i < 2; ++i)
#pragma unroll
            for (int j = 0; j < 4; ++j) {
                int col = wcol + j * 16 + cl;
#pragma unroll
                for (int r = 0; r < 4; ++r) {
                    int row = wrow + i * 16 + r4 + r;
                    int byte = (row * 256 + col * 2) ^ ((row & 7) << 4);
                    *reinterpret_cast<_Float16*>(Cs + byte) = (_Float16)acc[i][j][r];
                }
            }
    }
    __syncthreads();

#pragma unroll
    for (int it = 0; it < 4; ++it) {
        int lin = tid + it * 256;
        int row = lin >> 4, chunk = lin & 15;
        int gr = row0 + row;
        if (gr < M) {
            int byte = (row * 256 + chunk * 16) ^ ((row & 7) << 4);
            *reinterpret_cast<uint4*>(C16 + (size_t)gr * DH + col0 + chunk * 8) =
                *reinterpret_cast<const uint4*>(Cs + byte);
        }
    }

    // fused el/er: this block's 128 cols are one full head component
    {
        int r = lane >> 2, q = lane & 3;
        int row = wave * 16 + r;
        const float* alg = alp + col0;
        const float* arg = arp + col0;
        float els = 0.f, ers = 0.f;
#pragma unroll
        for (int kk = 0; kk < 4; ++kk) {
            int c0 = q * 32 + kk * 8;
            int byte = (row * 256 + c0 * 2) ^ ((row & 7) << 4);
            uint4 u = *reinterpret_cast<const uint4*>(Cs + byte);
            const _Float16* hv = (const _Float16*)&u;
#pragma unroll
            for (int t = 0; t < 8; ++t) {
                float hvv = (float)hv[t];
                els = fmaf(hvv, alg[c0 + t], els);
                ers = fmaf(hvv, arg[c0 + t], ers);
            }
        }
        els += __shfl_xor(els, 1); els += __shfl_xor(els, 2);
        ers += __shfl_xor(ers, 1); ers += __shfl_xor(ers, 2);
        int gr = row0 + row;
        if (q == 0 && gr < M) {
            el[gr * 2 + blockIdx.y] = els;
            er[gr * 2 + blockIdx.y] = ers;
        }
    }
}

// ---------------- aggregation: wave-per-node softmax + fp16 gather ----------------
// FINAL=false: write relu'd node row to g (fp16).
// FINAL=true : skip g store; project row onto fcW halves, write p[node] (float4).

template<bool FINAL>
__global__ __launch_bounds__(256) void k_agg(const _Float16* __restrict__ h,
                                             const float2* __restrict__ el2,
                                             const float2* __restrict__ er2,
                                             const int* __restrict__ row_ptr,
                                             const int* __restrict__ csr_src,
                                             const float* __restrict__ bias,
                                             _Float16* __restrict__ g,
                                             const float* __restrict__ fcW,
                                             float* __restrict__ p, int N) {
    __shared__ int    s_idx[4][CAP];
    __shared__ float2 s_a[4][CAP];

    int w = threadIdx.x >> 6, lane = threadIdx.x & 63;
    int node = blockIdx.x * 4 + w;
    if (node >= N) return;    // no block-wide syncs anywhere
    int beg = row_ptr[node];
    int deg = row_ptr[node + 1] - beg;
    float2 er = er2[node];
    bool lo = lane < 32;

    // phase 1: scores + wave max
    float m0 = -__builtin_inff(), m1 = -__builtin_inff();
    for (int i = lane; i < deg; i += 64) {
        int s = csr_src[beg + i];
        float2 el = el2[s];
        float sc0 = el.x + er.x; sc0 = sc0 > 0.f ? sc0 : NEG * sc0;
        float sc1 = el.y + er.y; sc1 = sc1 > 0.f ? sc1 : NEG * sc1;
        if (i < CAP) { s_idx[w][i] = s; s_a[w][i] = make_float2(sc0, sc1); }
        m0 = fmaxf(m0, sc0);
        m1 = fmaxf(m1, sc1);
    }
#pragma unroll
    for (int off = 32; off; off >>= 1) {
        m0 = fmaxf(m0, __shfl_xor(m0, off));
        m1 = fmaxf(m1, __shfl_xor(m1, off));
    }

    // phase 2: exp + wave sum
    float sum0 = 0.f, sum1 = 0.f;
    for (int i = lane; i < deg; i += 64) {
        float2 sc;
        if (i < CAP) sc = s_a[w][i];
        else {
            int s = csr_src[beg + i];
            float2 el = el2[s];
            sc.x = el.x + er.x; sc.x = sc.x > 0.f ? sc.x : NEG * sc.x;
            sc.y = el.y + er.y; sc.y = sc.y > 0.f ? sc.y : NEG * sc.y;
        }
        float e0 = __expf(sc.x - m0);
        float e1 = __expf(sc.y - m1);
        if (i < CAP) s_a[w][i] = make_float2(e0, e1);
        sum0 += e0;
        sum1 += e1;
    }
#pragma unroll
    for (int off = 32; off; off >>= 1) {
        sum0 += __shfl_xor(sum0, off);
        sum1 += __shfl_xor(sum1, off);
    }
    float S   = lo ? sum0 : sum1;
    float inv = S > 0.f ? 1.f / S : 0.f;
    float mh  = lo ? m0 : m1;
    float erh = lo ? er.x : er.y;

    // phase 3: fp16 gather (8B/lane/edge), 8 edges in flight
    const _Float16* hp = h + lane * 4;
    float4 acc = make_float4(0.f, 0.f, 0.f, 0.f);

#define FETCH(I, S_, A_)                                                    \
    do {                                                                     \
        int _i = (I);                                                        \
        if (_i < CAP) {                                                      \
            S_ = s_idx[w][_i];                                               \
            float2 _a2 = s_a[w][_i];                                         \
            A_ = lo ? _a2.x : _a2.y;                                         \
        } else {                                                             \
            S_ = csr_src[beg + _i];                                          \
            float2 _el = el2[S_];                                            \
            float _sc = (lo ? _el.x : _el.y) + erh;                          \
            _sc = _sc > 0.f ? _sc : NEG * _sc;                               \
            A_ = __expf(_sc - mh);                                           \
        }                                                                    \
    } while (0)

#define ACCUM(V, A_)                                                         \
    do {                                                                     \
        const _Float16* _hv = reinterpret_cast<const _Float16*>(&(V));       \
        acc.x = fmaf(A_, (float)_hv[0], acc.x);                              \
        acc.y = fmaf(A_, (float)_hv[1], acc.y);                              \
        acc.z = fmaf(A_, (float)_hv[2], acc.z);                              \
        acc.w = fmaf(A_, (float)_hv[3], acc.w);                              \
    } while (0)

    int i = 0;
    for (; i + 8 <= deg; i += 8) {
        int ss[8];
        float aa[8];
#pragma unroll
        for (int u = 0; u < 8; ++u) FETCH(i + u, ss[u], aa[u]);
        uint2 vv[8];
#pragma unroll
        for (int u = 0; u < 8; ++u)
            vv[u] = *reinterpret_cast<const uint2*>(hp + (size_t)ss[u] * DH);
#pragma unroll
        for (int u = 0; u < 8; ++u) ACCUM(vv[u], aa[u]);
    }
    for (; i + 4 <= deg; i += 4) {
        int ss[4];
        float aa[4];
#pragma unroll
        for (int u = 0; u < 4; ++u) FETCH(i + u, ss[u], aa[u]);
        uint2 vv[4];
#pragma unroll
        for (int u = 0; u < 4; ++u)
            vv[u] = *reinterpret_cast<const uint2*>(hp + (size_t)ss[u] * DH);
#pragma unroll
        for (int u = 0; u < 4; ++u) ACCUM(vv[u], aa[u]);
    }
    for (; i < deg; ++i) {
        int s;
        float a;
        FETCH(i, s, a);
        uint2 v = *reinterpret_cast<const uint2*>(hp + (size_t)s * DH);
        ACCUM(v, a);
    }
#undef FETCH
#undef ACCUM

    float4 b = *reinterpret_cast<const float4*>(bias + lane * 4);
    float o0 = fmaxf(fmaf(acc.x, inv, b.x), 0.f);
    float o1 = fmaxf(fmaf(acc.y, inv, b.y), 0.f);
    float o2 = fmaxf(fmaf(acc.z, inv, b.z), 0.f);
    float o3 = fmaxf(fmaf(acc.w, inv, b.w), 0.f);

    if (!FINAL) {
        half4 o = { (_Float16)o0, (_Float16)o1, (_Float16)o2, (_Float16)o3 };
        *reinterpret_cast<half4*>(g + (size_t)node * DH + lane * 4) = o;
    } else {
        // fused classifier projection: p[node] = (row·fcW_top, row·fcW_bot)
        int d = lane * 4;
        float a0 = 0.f, a1 = 0.f, a2 = 0.f, a3 = 0.f;
        float ov[4] = {o0, o1, o2, o3};
#pragma unroll
        for (int t = 0; t < 4; ++t) {
            float2 wt = *reinterpret_cast<const float2*>(&fcW[(d + t) * 2]);
            float2 wb = *reinterpret_cast<const float2*>(&fcW[(DH + d + t) * 2]);
            a0 = fmaf(ov[t], wt.x, a0);
            a1 = fmaf(ov[t], wt.y, a1);
            a2 = fmaf(ov[t], wb.x, a2);
            a3 = fmaf(ov[t], wb.y, a3);
        }
#pragma unroll
        for (int off = 32; off; off >>= 1) {
            a0 += __shfl_xor(a0, off);
            a1 += __shfl_xor(a1, off);
            a2 += __shfl_xor(a2, off);
            a3 += __shfl_xor(a3, off);
        }
        if (lane == 0)
            *reinterpret_cast<float4*>(&p[(size_t)node * 4]) = make_float4(a0, a1, a2, a3);
    }
}

// ---------------- edge output ----------------

__global__ void k_edgeout(const float* __restrict__ p,
                          const int* __restrict__ src,
                          const int* __restrict__ dst,
                          const float* __restrict__ fcb,
                          float* __restrict__ out, int E) {
    int e = blockIdx.x * blockDim.x + threadIdx.x;
    if (e >= E) return;
    int s = src[e], d = dst[e];
    float2 ps = *reinterpret_cast<const float2*>(&p[(size_t)s * 4]);
    float2 pd = *reinterpret_cast<const float2*>(&p[(size_t)d * 4 + 2]);
    float2 o;
    o.x = ps.x + pd.x + fcb[0];
    o.y = ps.y + pd.y + fcb[1];
    *reinterpret_cast<float2*>(&out[(size_t)e * 2]) = o;
}

// ---------------- launch ----------------

extern "C" void kernel_launch(void* const* d_in, const int* in_sizes, int n_in,
                              void* d_out, int out_size, void* d_ws, size_t ws_size,
                              hipStream_t stream) {
    const float* x   = (const float*)d_in[0];
    const float* rep = (const float*)d_in[1];
    const int*   src = (const int*)d_in[2];
    const int*   dst = (const int*)d_in[3];
    const float* W1  = (const float*)d_in[4];
    const float* al1 = (const float*)d_in[5];
    const float* ar1 = (const float*)d_in[6];
    const float* b1  = (const float*)d_in[7];
    const float* W2  = (const float*)d_in[8];
    const float* al2 = (const float*)d_in[9];
    const float* ar2 = (const float*)d_in[10];
    const float* b2  = (const float*)d_in[11];
    const float* fcW = (const float*)d_in[12];
    const float* fcb = (const float*)d_in[13];
    float* out = (float*)d_out;

    int N = in_sizes[0] / 64;   // 25000
    int E = in_sizes[2];        // 400000

    char* ws = (char*)d_ws;
    size_t off = 0;
    auto alloc = [&](size_t bytes) -> void* {
        void* ptr = ws + off;
        off = (off + bytes + 255) & ~(size_t)255;
        return ptr;
    };
    int*       deg     = (int*)alloc((size_t)32768 * 4);    // zero-padded for vector scan
    int*       row_ptr = (int*)alloc((size_t)(N + 1) * 4);
    int*       cursor  = (int*)alloc((size_t)N * 4);
    int*       csr_src = (int*)alloc((size_t)E * 4);
    _Float16*  feat16  = (_Float16*)alloc((size_t)N * 128 * 2);
    _Float16*  W1T     = (_Float16*)alloc((size_t)256 * 128 * 2);
    _Float16*  W2T     = (_Float16*)alloc((size_t)256 * 256 * 2);
    _Float16*  h16     = (_Float16*)alloc((size_t)N * DH * 2);
    _Float16*  g16     = (_Float16*)alloc((size_t)N * DH * 2);
    float*     el      = (float*)alloc((size_t)N * 2 * 4);
    float*     er      = (float*)alloc((size_t)N * 2 * 4);
    float*     p       = (float*)alloc((size_t)N * 4 * 4);
    (void)alloc(65536);   // tail slack: gemm stage reads up to 63 rows past M

    hipMemsetAsync(deg, 0, (size_t)32768 * 4, stream);

    int eb = (E + 255) / 256;
    int nb4 = (N + 3) / 4;
    int prep_blocks = (N * 32 + 256 * 128 + 256 * 256 + E + 255) / 256;

    k_prep<<<prep_blocks, 256, 0, stream>>>(x, rep, W1, W2, dst, feat16, W1T, W2T, deg, N, E);
    k_scan<<<1, 1024, 0, stream>>>(deg, row_ptr, cursor, N);
    k_fill<<<eb, 256, 0, stream>>>(src, dst, cursor, csr_src, E);

    dim3 ggrid((N + GBM - 1) / GBM, DH / GBN);
    // layer 1 (gemm writes h16 AND el/er)
    k_gemm16<128><<<ggrid, 256, 0, stream>>>(feat16, W1T, h16, al1, ar1, el, er, N);
    k_agg<false><<<nb4, 256, 0, stream>>>(h16, (const float2*)el, (const float2*)er,
                                          row_ptr, csr_src, b1, g16, nullptr, nullptr, N);
    // layer 2
    k_gemm16<256><<<ggrid, 256, 0, stream>>>(g16, W2T, h16, al2, ar2, el, er, N);
    k_agg<true><<<nb4, 256, 0, stream>>>(h16, (const float2*)el, (const float2*)er,
                                         row_ptr, csr_src, b2, nullptr, fcW, p, N);
    // edge output
    k_edgeout<<<eb, 256, 0, stream>>>(p, src, dst, fcb, out, E);
}